// Round 1
// baseline (1584.369 us; speedup 1.0000x reference)
//
#include <hip/hip_runtime.h>
#include <cstdint>
#include <cstddef>

constexpr int D_   = 256;
constexpr int H_   = 8;
constexpr int DH_  = 32;
constexpr int NK_  = 18;
constexpr int NQ_  = 100;
constexpr int BS_  = 8;
constexpr int T_   = NQ_ * BS_ * NK_;   // 14400 tokens
constexpr int LIN_ = 13294;
constexpr int LQ_  = NQ_ * NK_;         // 1800

// ---------------------------------------------------------------------------
// GEMM: C[m,n] = sum_k A[m,k] * W[n,k] + bias[n]   (A: MxK via AMODE mapping,
// W: NxK row-major, C: MxN row-major).  Optional ReLU.
// AMODE 0: plain rows.
// AMODE 1: m = b*LIN + i  -> A row (i*BS + b)           (memory (LIN,BS,D))
// AMODE 2: m = b*1800+lq, lq=qq*18+kk -> A row qq*144 + b*18 + kk  (token map)
// ---------------------------------------------------------------------------
template<int AMODE, bool RELU>
__global__ __launch_bounds__(256) void gemm_nt(
    const float* __restrict__ A, const float* __restrict__ W,
    const float* __restrict__ bias, float* __restrict__ C,
    int M, int N, int K) {
  __shared__ float As[16][64];
  __shared__ float Ws[16][64];
  const int bm = blockIdx.y * 64, bn = blockIdx.x * 64;
  const int tid = threadIdx.x;
  const int lr = tid >> 2;          // 0..63 tile row
  const int lc = (tid & 3) * 4;     // k offset (float4)
  const int tx = tid & 15, ty = tid >> 4;

  const int m_load = bm + lr;
  const bool mval = m_load < M;
  const float* arow;
  {
    int mm = mval ? m_load : 0;
    if (AMODE == 0) {
      arow = A + (size_t)mm * K;
    } else if (AMODE == 1) {
      int b = mm / LIN_, i = mm - b * LIN_;
      arow = A + ((size_t)i * BS_ + b) * K;
    } else {
      int b = mm / LQ_, lq = mm - b * LQ_;
      int qq = lq / NK_, kk = lq - qq * NK_;
      arow = A + ((size_t)qq * (BS_ * NK_) + b * NK_ + kk) * K;
    }
  }
  const float* wrow = W + (size_t)(bn + lr) * K;

  float acc[4][4] = {};
  for (int k0 = 0; k0 < K; k0 += 16) {
    float4 av = mval ? *(const float4*)(arow + k0 + lc)
                     : make_float4(0.f, 0.f, 0.f, 0.f);
    float4 wv = *(const float4*)(wrow + k0 + lc);
    As[lc + 0][lr] = av.x; As[lc + 1][lr] = av.y;
    As[lc + 2][lr] = av.z; As[lc + 3][lr] = av.w;
    Ws[lc + 0][lr] = wv.x; Ws[lc + 1][lr] = wv.y;
    Ws[lc + 2][lr] = wv.z; Ws[lc + 3][lr] = wv.w;
    __syncthreads();
#pragma unroll
    for (int k = 0; k < 16; ++k) {
      float4 a = *(const float4*)&As[k][ty * 4];
      float4 w = *(const float4*)&Ws[k][tx * 4];
      acc[0][0] += a.x * w.x; acc[0][1] += a.x * w.y;
      acc[0][2] += a.x * w.z; acc[0][3] += a.x * w.w;
      acc[1][0] += a.y * w.x; acc[1][1] += a.y * w.y;
      acc[1][2] += a.y * w.z; acc[1][3] += a.y * w.w;
      acc[2][0] += a.z * w.x; acc[2][1] += a.z * w.y;
      acc[2][2] += a.z * w.z; acc[2][3] += a.z * w.w;
      acc[3][0] += a.w * w.x; acc[3][1] += a.w * w.y;
      acc[3][2] += a.w * w.z; acc[3][3] += a.w * w.w;
    }
    __syncthreads();
  }
  float4 b4 = *(const float4*)(bias + bn + tx * 4);
#pragma unroll
  for (int j = 0; j < 4; ++j) {
    int m = bm + ty * 4 + j;
    if (m >= M) continue;
    float4 o;
    o.x = acc[j][0] + b4.x; o.y = acc[j][1] + b4.y;
    o.z = acc[j][2] + b4.z; o.w = acc[j][3] + b4.w;
    if (RELU) {
      o.x = fmaxf(o.x, 0.f); o.y = fmaxf(o.y, 0.f);
      o.z = fmaxf(o.z, 0.f); o.w = fmaxf(o.w, 0.f);
    }
    *(float4*)(C + (size_t)m * N + bn + tx * 4) = o;
  }
}

// ---------------------------------------------------------------------------
// Residual + LayerNorm (+ optional pos add): Y = LN(X + R)*g + b (+ POS)
// One wave per row of 256.
// ---------------------------------------------------------------------------
__global__ __launch_bounds__(256) void ln_res(
    const float* __restrict__ X, const float* __restrict__ R,
    const float* __restrict__ G, const float* __restrict__ Bb,
    const float* __restrict__ POS, float* __restrict__ Y, int T) {
  int row = blockIdx.x * 4 + (threadIdx.x >> 6);
  int lane = threadIdx.x & 63;
  if (row >= T) return;
  size_t off = (size_t)row * 256 + lane * 4;
  float4 xv = *(const float4*)(X + off);
  float4 rv = *(const float4*)(R + off);
  float4 v = make_float4(xv.x + rv.x, xv.y + rv.y, xv.z + rv.z, xv.w + rv.w);
  float s = v.x + v.y + v.z + v.w;
#pragma unroll
  for (int o = 32; o; o >>= 1) s += __shfl_xor(s, o);
  float mu = s * (1.0f / 256.0f);
  float4 c = make_float4(v.x - mu, v.y - mu, v.z - mu, v.w - mu);
  float q = c.x * c.x + c.y * c.y + c.z * c.z + c.w * c.w;
#pragma unroll
  for (int o = 32; o; o >>= 1) q += __shfl_xor(q, o);
  float rs = rsqrtf(q * (1.0f / 256.0f) + 1e-5f);
  float4 g = *(const float4*)(G + lane * 4);
  float4 bb = *(const float4*)(Bb + lane * 4);
  float4 o4;
  o4.x = c.x * rs * g.x + bb.x;
  o4.y = c.y * rs * g.y + bb.y;
  o4.z = c.z * rs * g.z + bb.z;
  o4.w = c.w * rs * g.w + bb.w;
  if (POS) {
    float4 p = *(const float4*)(POS + off);
    o4.x += p.x; o4.y += p.y; o4.z += p.z; o4.w += p.w;
  }
  *(float4*)(Y + off) = o4;
}

// ---------------------------------------------------------------------------
// Across-attention: seq S=100, batch B=144 (= BS*NK), token = s*144 + b.
// One block per (b, h). QKV rows in token order, layout [tok][3*256].
// ---------------------------------------------------------------------------
__global__ __launch_bounds__(256) void attn_across(
    const float* __restrict__ QKV, float* __restrict__ O) {
  __shared__ float Qs[100][33];
  __shared__ float Ks[100][33];
  __shared__ float Vs[100][33];
  __shared__ float Ps[4][104];
  const int b = blockIdx.x >> 3, h = blockIdx.x & 7;
  const int tid = threadIdx.x;
  for (int idx = tid; idx < 100 * 32; idx += 256) {
    int r = idx >> 5, d = idx & 31;
    size_t base = ((size_t)r * 144 + b) * 768 + h * 32 + d;
    Qs[r][d] = QKV[base];
    Ks[r][d] = QKV[base + 256];
    Vs[r][d] = QKV[base + 512];
  }
  __syncthreads();
  const int wave = tid >> 6, lane = tid & 63;
  const float scale = 0.17677669529663687f;  // 1/sqrt(32)
  for (int s = wave; s < 100; s += 4) {
    float s0 = 0.f, s1 = 0.f;
    const int k1 = 64 + lane;
    const bool k1v = k1 < 100;
#pragma unroll 8
    for (int d = 0; d < 32; ++d) {
      float qd = Qs[s][d];
      s0 += qd * Ks[lane][d];
      s1 += qd * (k1v ? Ks[k1 & 127][d] : 0.f);
    }
    s0 *= scale;
    s1 = k1v ? s1 * scale : -1e30f;
    float mx = fmaxf(s0, s1);
#pragma unroll
    for (int o = 32; o; o >>= 1) mx = fmaxf(mx, __shfl_xor(mx, o));
    float e0 = __expf(s0 - mx);
    float e1 = k1v ? __expf(s1 - mx) : 0.f;
    float sum = e0 + e1;
#pragma unroll
    for (int o = 32; o; o >>= 1) sum += __shfl_xor(sum, o);
    float inv = 1.f / sum;
    Ps[wave][lane] = e0 * inv;
    if (lane < 40) Ps[wave][64 + lane] = (lane < 36) ? e1 * inv : 0.f;
    __syncthreads();
    int d = lane & 31, half = lane >> 5;
    float o = 0.f;
    int kb = half * 50;
    for (int k = kb; k < kb + 50; ++k) o += Ps[wave][k] * Vs[k][d];
    o += __shfl_xor(o, 32);
    if (lane < 32) O[((size_t)s * 144 + b) * 256 + h * 32 + d] = o;
    __syncthreads();
  }
}

// ---------------------------------------------------------------------------
// Within-attention: seq S=18 (NK), batch B=800 (= NQ*BS).  Mask is a uniform
// constant -> softmax-invariant -> ignored.  token = qq*144 + bb*18 + k.
// One block per b; wave w handles heads 2w, 2w+1.
// ---------------------------------------------------------------------------
__global__ __launch_bounds__(256) void attn_within(
    const float* __restrict__ QKV, float* __restrict__ O) {
  __shared__ float Qs[18 * 257];
  __shared__ float Ks[18 * 257];
  __shared__ float Vs[18 * 257];
  __shared__ float Ps[4][20];
  const int b = blockIdx.x;
  const int qq = b >> 3, bb = b & 7;
  const int tid = threadIdx.x;
  for (int idx = tid; idx < 18 * 256; idx += 256) {
    int r = idx >> 8, j = idx & 255;
    size_t tok = (size_t)qq * 144 + bb * 18 + r;
    size_t base = tok * 768 + j;
    Qs[r * 257 + j] = QKV[base];
    Ks[r * 257 + j] = QKV[base + 256];
    Vs[r * 257 + j] = QKV[base + 512];
  }
  __syncthreads();
  const int wave = tid >> 6, lane = tid & 63;
  const float scale = 0.17677669529663687f;
  for (int hh = 0; hh < 2; ++hh) {
    const int h = wave * 2 + hh;
    for (int s = 0; s < 18; ++s) {
      float sc = 0.f;
      const bool lv = lane < 18;
      const int lrow = lv ? lane : 0;
#pragma unroll 8
      for (int d = 0; d < 32; ++d) {
        sc += Qs[s * 257 + h * 32 + d] * Ks[lrow * 257 + h * 32 + d];
      }
      sc = lv ? sc * scale : -1e30f;
      float mx = sc;
#pragma unroll
      for (int o = 32; o; o >>= 1) mx = fmaxf(mx, __shfl_xor(mx, o));
      float e = lv ? __expf(sc - mx) : 0.f;
      float sum = e;
#pragma unroll
      for (int o = 32; o; o >>= 1) sum += __shfl_xor(sum, o);
      if (lv) Ps[wave][lane] = e / sum;
      __syncthreads();
      int d = lane & 31;
      float o = 0.f;
#pragma unroll
      for (int k = 0; k < 18; ++k) o += Ps[wave][k] * Vs[k * 257 + h * 32 + d];
      if (lane < 32) {
        size_t tok = (size_t)qq * 144 + bb * 18 + s;
        O[tok * 256 + h * 32 + d] = o;
      }
      __syncthreads();
    }
  }
}

// ---------------------------------------------------------------------------
// Deformable sampling: one block per (b, lq); thread = (h, d).
// OFF: [m][256] (h,l,p,2), AW: [m][128] (h, l*4+p), V: [(b*LIN+i)][256],
// REF original layout (1800, 8, 4, 2).  Output written in token order.
// ---------------------------------------------------------------------------
__global__ __launch_bounds__(256) void deform_sample(
    const float* __restrict__ OFF, const float* __restrict__ AW,
    const float* __restrict__ V, const float* __restrict__ REF,
    float* __restrict__ OUT) {
  const int m = blockIdx.x;
  const int b = m / LQ_, lq = m - b * LQ_;
  const int qq = lq / NK_, kk = lq - qq * NK_;
  __shared__ float aw_sm[8][16];
  const int tid = threadIdx.x;
  if (tid < 128) {
    int h = tid >> 4, j = tid & 15;
    float v = AW[(size_t)m * 128 + h * 16 + j];
    float mx = v;
#pragma unroll
    for (int o = 8; o; o >>= 1) mx = fmaxf(mx, __shfl_xor(mx, o, 16));
    float e = __expf(v - mx);
    float sm = e;
#pragma unroll
    for (int o = 8; o; o >>= 1) sm += __shfl_xor(sm, o, 16);
    aw_sm[h][j] = e / sm;
  }
  __syncthreads();
  const int h = tid >> 5, d = tid & 31;
  const int WH[4] = {100, 50, 25, 13};
  const int ST[4] = {0, 10000, 12500, 13125};
  const size_t vbase = (size_t)b * LIN_;
  const int hd = h * 32 + d;
  float acc = 0.f;
#pragma unroll
  for (int li = 0; li < 4; ++li) {
    const int Wl = WH[li], Hl = WH[li], st = ST[li];
    const float fW = (float)Wl, fH = (float)Hl;
    float rx = REF[(((size_t)lq * 8 + b) * 4 + li) * 2 + 0];
    float ry = REF[(((size_t)lq * 8 + b) * 4 + li) * 2 + 1];
#pragma unroll
    for (int p = 0; p < 4; ++p) {
      float ox = OFF[(size_t)m * 256 + h * 32 + li * 8 + p * 2 + 0];
      float oy = OFF[(size_t)m * 256 + h * 32 + li * 8 + p * 2 + 1];
      float x = (rx + ox / fW) * fW - 0.5f;
      float y = (ry + oy / fH) * fH - 0.5f;
      float x0f = floorf(x), y0f = floorf(y);
      float lx = x - x0f, ly = y - y0f;
      int x0 = (int)x0f, y0 = (int)y0f;
      float a = aw_sm[h][li * 4 + p];
      float c00, c10, c01, c11;
      {
        int xi = x0, yi = y0;
        bool va = (xi >= 0) && (xi < Wl) && (yi >= 0) && (yi < Hl);
        int xc = min(max(xi, 0), Wl - 1), yc = min(max(yi, 0), Hl - 1);
        float v = V[(vbase + st + yc * Wl + xc) * 256 + hd];
        c00 = va ? v : 0.f;
      }
      {
        int xi = x0 + 1, yi = y0;
        bool va = (xi >= 0) && (xi < Wl) && (yi >= 0) && (yi < Hl);
        int xc = min(max(xi, 0), Wl - 1), yc = min(max(yi, 0), Hl - 1);
        float v = V[(vbase + st + yc * Wl + xc) * 256 + hd];
        c10 = va ? v : 0.f;
      }
      {
        int xi = x0, yi = y0 + 1;
        bool va = (xi >= 0) && (xi < Wl) && (yi >= 0) && (yi < Hl);
        int xc = min(max(xi, 0), Wl - 1), yc = min(max(yi, 0), Hl - 1);
        float v = V[(vbase + st + yc * Wl + xc) * 256 + hd];
        c01 = va ? v : 0.f;
      }
      {
        int xi = x0 + 1, yi = y0 + 1;
        bool va = (xi >= 0) && (xi < Wl) && (yi >= 0) && (yi < Hl);
        int xc = min(max(xi, 0), Wl - 1), yc = min(max(yi, 0), Hl - 1);
        float v = V[(vbase + st + yc * Wl + xc) * 256 + hd];
        c11 = va ? v : 0.f;
      }
      float bil = c00 * (1.f - lx) * (1.f - ly) + c10 * lx * (1.f - ly) +
                  c01 * (1.f - lx) * ly + c11 * lx * ly;
      acc += a * bil;
    }
  }
  size_t tok = (size_t)qq * 144 + b * 18 + kk;
  OUT[tok * 256 + hd] = acc;
}

// ---------------------------------------------------------------------------
extern "C" void kernel_launch(void* const* d_in, const int* in_sizes, int n_in,
                              void* d_out, int out_size, void* d_ws, size_t ws_size,
                              hipStream_t stream) {
  const float* tgt  = (const float*)d_in[0];
  const float* pos  = (const float*)d_in[1];
  const float* ref  = (const float*)d_in[2];
  const float* mem  = (const float*)d_in[3];
  const float* across_in_w  = (const float*)d_in[4];
  const float* across_in_b  = (const float*)d_in[5];
  const float* across_out_w = (const float*)d_in[6];
  const float* across_out_b = (const float*)d_in[7];
  const float* within_in_w  = (const float*)d_in[8];
  const float* within_in_b  = (const float*)d_in[9];
  const float* within_out_w = (const float*)d_in[10];
  const float* within_out_b = (const float*)d_in[11];
  const float* off_w  = (const float*)d_in[12];
  const float* off_b  = (const float*)d_in[13];
  const float* aw_w   = (const float*)d_in[14];
  const float* aw_b   = (const float*)d_in[15];
  const float* val_w  = (const float*)d_in[16];
  const float* val_b  = (const float*)d_in[17];
  const float* msout_w = (const float*)d_in[18];
  const float* msout_b = (const float*)d_in[19];
  const float* lin1_w  = (const float*)d_in[20];
  const float* lin1_b  = (const float*)d_in[21];
  const float* lin2_w  = (const float*)d_in[22];
  const float* lin2_b  = (const float*)d_in[23];
  const float* lin1p_w = (const float*)d_in[24];
  const float* lin1p_b = (const float*)d_in[25];
  const float* lin2p_w = (const float*)d_in[26];
  const float* lin2p_b = (const float*)d_in[27];
  const float* across_norm_g = (const float*)d_in[28];
  const float* across_norm_b = (const float*)d_in[29];
  const float* within_norm_g = (const float*)d_in[30];
  const float* within_norm_b = (const float*)d_in[31];
  const float* norm1_g = (const float*)d_in[32];
  const float* norm1_b = (const float*)d_in[33];
  const float* norm2_g = (const float*)d_in[34];
  const float* norm2_b = (const float*)d_in[35];
  const float* norm2p_g = (const float*)d_in[36];
  const float* norm2p_b = (const float*)d_in[37];

  float* ws = (float*)d_ws;
  float* QKV = ws;                         // 14400*768  = 11,059,200
  float* AO  = QKV + (size_t)T_ * 768;     // 14400*256  =  3,686,400
  float* CT  = AO + (size_t)T_ * 256;      // 14400*256  =  3,686,400
  float* U   = CT + (size_t)T_ * 256;      // max(8*13294*256, 14400*1024)
  float* Bt  = (float*)d_out;              // t2 buffer aliased on d_out
  float* AWb = QKV;                        // 14400*128 during deform
  float* SMP = QKV + (size_t)T_ * 128;     // 14400*256 during deform

  dim3 blk(256);
  const int MT = T_;                  // 14400
  const int MV = BS_ * LIN_;          // 106352
  dim3 gLN((MT + 3) / 4);

  // 1. across in-proj -> QKV
  gemm_nt<0, false><<<dim3(768 / 64, MT / 64), blk, 0, stream>>>(
      tgt, across_in_w, across_in_b, QKV, MT, 768, 256);
  // 2. across attention -> AO (token order)
  attn_across<<<dim3(144 * 8), blk, 0, stream>>>(QKV, AO);
  // 3. across out-proj -> Bt
  gemm_nt<0, false><<<dim3(256 / 64, MT / 64), blk, 0, stream>>>(
      AO, across_out_w, across_out_b, Bt, MT, 256, 256);
  // 4. tgt = LN(tgt + t2) + pos -> CT
  ln_res<<<gLN, blk, 0, stream>>>(tgt, Bt, across_norm_g, across_norm_b, pos, CT, MT);
  // 5. value projection (memory layout map) -> U
  gemm_nt<1, false><<<dim3(256 / 64, (MV + 63) / 64), blk, 0, stream>>>(
      mem, val_w, val_b, U, MV, 256, 256);
  // 6. offsets -> AO   (query rows via token map)
  gemm_nt<2, false><<<dim3(256 / 64, MT / 64), blk, 0, stream>>>(
      CT, off_w, off_b, AO, MT, 256, 256);
  // 7. attention weights -> AWb
  gemm_nt<2, false><<<dim3(128 / 64, MT / 64), blk, 0, stream>>>(
      CT, aw_w, aw_b, AWb, MT, 128, 256);
  // 8. bilinear sampling + weighted sum -> SMP (token order)
  deform_sample<<<dim3(BS_ * LQ_), blk, 0, stream>>>(AO, AWb, U, ref, SMP);
  // 9. msout projection -> Bt
  gemm_nt<0, false><<<dim3(256 / 64, MT / 64), blk, 0, stream>>>(
      SMP, msout_w, msout_b, Bt, MT, 256, 256);
  // 10. norm1 (in place on CT)
  ln_res<<<gLN, blk, 0, stream>>>(CT, Bt, norm1_g, norm1_b, nullptr, CT, MT);
  // 11-12. FFN
  gemm_nt<0, true><<<dim3(1024 / 64, MT / 64), blk, 0, stream>>>(
      CT, lin1_w, lin1_b, U, MT, 1024, 256);
  gemm_nt<0, false><<<dim3(256 / 64, MT / 64), blk, 0, stream>>>(
      U, lin2_w, lin2_b, Bt, MT, 256, 1024);
  // 13. norm2 + pos
  ln_res<<<gLN, blk, 0, stream>>>(CT, Bt, norm2_g, norm2_b, pos, CT, MT);
  // 14. within in-proj -> QKV
  gemm_nt<0, false><<<dim3(768 / 64, MT / 64), blk, 0, stream>>>(
      CT, within_in_w, within_in_b, QKV, MT, 768, 256);
  // 15. within attention -> AO
  attn_within<<<dim3(NQ_ * BS_), blk, 0, stream>>>(QKV, AO);
  // 16. within out-proj -> Bt
  gemm_nt<0, false><<<dim3(256 / 64, MT / 64), blk, 0, stream>>>(
      AO, within_out_w, within_out_b, Bt, MT, 256, 256);
  // 17. within_norm
  ln_res<<<gLN, blk, 0, stream>>>(CT, Bt, within_norm_g, within_norm_b, nullptr, CT, MT);
  // 18-19. FFN p
  gemm_nt<0, true><<<dim3(1024 / 64, MT / 64), blk, 0, stream>>>(
      CT, lin1p_w, lin1p_b, U, MT, 1024, 256);
  gemm_nt<0, false><<<dim3(256 / 64, MT / 64), blk, 0, stream>>>(
      U, lin2p_w, lin2p_b, Bt, MT, 256, 1024);
  // 20. final norm2p -> d_out
  ln_res<<<gLN, blk, 0, stream>>>(CT, Bt, norm2p_g, norm2p_b, nullptr, (float*)d_out, MT);
}

// Round 2
// 720.382 us; speedup vs baseline: 2.1993x; 2.1993x over previous
//
#include <hip/hip_runtime.h>
#include <cstdint>
#include <cstddef>

constexpr int D_   = 256;
constexpr int NK_  = 18;
constexpr int NQ_  = 100;
constexpr int BS_  = 8;
constexpr int T_   = NQ_ * BS_ * NK_;   // 14400 tokens
constexpr int LIN_ = 13294;
constexpr int LQ_  = NQ_ * NK_;         // 1800

typedef __attribute__((ext_vector_type(8))) short bfv8;
typedef __attribute__((ext_vector_type(4))) float f32x4;

__device__ __forceinline__ ushort f2b(float f) {
  uint32_t u = __builtin_bit_cast(uint32_t, f);
  u += 0x7fffu + ((u >> 16) & 1u);
  return (ushort)(u >> 16);
}
__device__ __forceinline__ float b2f(ushort h) {
  uint32_t u = ((uint32_t)h) << 16;
  return __builtin_bit_cast(float, u);
}

// ---------------------------------------------------------------------------
// Weight conversion: all 12 GEMM weights f32 -> bf16 into one arena.
// ---------------------------------------------------------------------------
constexpr int WOF0  = 0;        // across_in_w 196608
constexpr int WOF1  = 196608;   // within_in_w 196608
constexpr int WOF2  = 393216;   // across_out_w 65536
constexpr int WOF3  = 458752;   // within_out_w 65536
constexpr int WOF4  = 524288;   // off_w 65536
constexpr int WOF5  = 589824;   // aw_w 32768
constexpr int WOF6  = 622592;   // val_w 65536
constexpr int WOF7  = 688128;   // msout_w 65536
constexpr int WOF8  = 753664;   // lin1_w 262144
constexpr int WOF9  = 1015808;  // lin2_w 262144
constexpr int WOF10 = 1277952;  // lin1p_w 262144
constexpr int WOF11 = 1540096;  // lin2p_w 262144
constexpr int WTOT  = 1802240;

__global__ __launch_bounds__(256) void conv_weights(
    const float* __restrict__ w0, const float* __restrict__ w1,
    const float* __restrict__ w2, const float* __restrict__ w3,
    const float* __restrict__ w4, const float* __restrict__ w5,
    const float* __restrict__ w6, const float* __restrict__ w7,
    const float* __restrict__ w8, const float* __restrict__ w9,
    const float* __restrict__ w10, const float* __restrict__ w11,
    ushort* __restrict__ out) {
  int i8 = (blockIdx.x * 256 + threadIdx.x) * 8;
  if (i8 >= WTOT) return;
  const float* src; int off;
  if      (i8 < WOF1)  { src = w0;  off = WOF0; }
  else if (i8 < WOF2)  { src = w1;  off = WOF1; }
  else if (i8 < WOF3)  { src = w2;  off = WOF2; }
  else if (i8 < WOF4)  { src = w3;  off = WOF3; }
  else if (i8 < WOF5)  { src = w4;  off = WOF4; }
  else if (i8 < WOF6)  { src = w5;  off = WOF5; }
  else if (i8 < WOF7)  { src = w6;  off = WOF6; }
  else if (i8 < WOF8)  { src = w7;  off = WOF7; }
  else if (i8 < WOF9)  { src = w8;  off = WOF8; }
  else if (i8 < WOF10) { src = w9;  off = WOF9; }
  else if (i8 < WOF11) { src = w10; off = WOF10; }
  else                 { src = w11; off = WOF11; }
  const float4 v0 = *(const float4*)(src + (i8 - off));
  const float4 v1 = *(const float4*)(src + (i8 - off) + 4);
  uint4 o;
  o.x = (uint)f2b(v0.x) | ((uint)f2b(v0.y) << 16);
  o.y = (uint)f2b(v0.z) | ((uint)f2b(v0.w) << 16);
  o.z = (uint)f2b(v1.x) | ((uint)f2b(v1.y) << 16);
  o.w = (uint)f2b(v1.z) | ((uint)f2b(v1.w) << 16);
  *(uint4*)(out + i8) = o;
}

// ---------------------------------------------------------------------------
// MFMA GEMM: C[m,n] = sum_k A[m,k]*W[n,k] + bias[n].
// A: bf16 (or f32 if AF32) rows via AMODE mapping; W: bf16 [N][K]; 128x128
// tile, BK=32, 4 waves each computing 64x64 via 16 x mfma_16x16x32_bf16.
// OUTMODE: 0 = f32, 1 = bf16, 2 = bf16 + relu.
// AMODE 0: plain. 1: m=b*LIN+i -> row i*BS+b. 2: m=b*1800+lq -> token map.
// ---------------------------------------------------------------------------
template<int AMODE, bool AF32, int OUTMODE>
__global__ __launch_bounds__(256) void gemm_mfma(
    const void* __restrict__ Av, const ushort* __restrict__ W,
    const float* __restrict__ bias, void* __restrict__ Cv,
    int M, int N, int K) {
  __shared__ ushort As[128][40];
  __shared__ ushort Bs[128][40];
  const int tid = threadIdx.x;
  const int bm = blockIdx.y * 128, bn = blockIdx.x * 128;
  const int r = tid >> 1, hf = tid & 1;

  int gm = bm + r; if (gm >= M) gm = M - 1;
  int asrc;
  if (AMODE == 0) {
    asrc = gm;
  } else if (AMODE == 1) {
    int b = gm / LIN_, i = gm - b * LIN_;
    asrc = i * BS_ + b;
  } else {
    int b = gm / LQ_, lq = gm - b * LQ_;
    int qq = lq / NK_, kk = lq - qq * NK_;
    asrc = qq * (BS_ * NK_) + b * NK_ + kk;
  }
  const float*  Af = (const float*)Av;
  const ushort* Ab = (const ushort*)Av;
  const ushort* wrow = W + (size_t)(bn + r) * K;

  const int wave = tid >> 6, lane = tid & 63;
  const int wm = (wave >> 1) * 64, wn = (wave & 1) * 64;
  const int fr = lane & 15, fk = lane >> 4;

  f32x4 acc[4][4] = {};
  for (int k0 = 0; k0 < K; k0 += 32) {
    if (AF32) {
      const float* p = Af + (size_t)asrc * K + k0 + hf * 16;
      float4 v0 = *(const float4*)p;
      float4 v1 = *(const float4*)(p + 4);
      float4 v2 = *(const float4*)(p + 8);
      float4 v3 = *(const float4*)(p + 12);
      ushort* d = &As[r][hf * 16];
      d[0]  = f2b(v0.x); d[1]  = f2b(v0.y); d[2]  = f2b(v0.z); d[3]  = f2b(v0.w);
      d[4]  = f2b(v1.x); d[5]  = f2b(v1.y); d[6]  = f2b(v1.z); d[7]  = f2b(v1.w);
      d[8]  = f2b(v2.x); d[9]  = f2b(v2.y); d[10] = f2b(v2.z); d[11] = f2b(v2.w);
      d[12] = f2b(v3.x); d[13] = f2b(v3.y); d[14] = f2b(v3.z); d[15] = f2b(v3.w);
    } else {
      const ushort* p = Ab + (size_t)asrc * K + k0 + hf * 16;
      uint4 u0 = *(const uint4*)p;
      uint4 u1 = *(const uint4*)(p + 8);
      *(uint4*)&As[r][hf * 16] = u0;
      *(uint4*)&As[r][hf * 16 + 8] = u1;
    }
    {
      const ushort* p = wrow + k0 + hf * 16;
      uint4 u0 = *(const uint4*)p;
      uint4 u1 = *(const uint4*)(p + 8);
      *(uint4*)&Bs[r][hf * 16] = u0;
      *(uint4*)&Bs[r][hf * 16 + 8] = u1;
    }
    __syncthreads();
    bfv8 a[4], b[4];
#pragma unroll
    for (int m = 0; m < 4; ++m)
      a[m] = *(const bfv8*)&As[wm + m * 16 + fr][fk * 8];
#pragma unroll
    for (int n = 0; n < 4; ++n)
      b[n] = *(const bfv8*)&Bs[wn + n * 16 + fr][fk * 8];
#pragma unroll
    for (int m = 0; m < 4; ++m)
#pragma unroll
      for (int n = 0; n < 4; ++n)
        acc[m][n] = __builtin_amdgcn_mfma_f32_16x16x32_bf16(a[m], b[n], acc[m][n], 0, 0, 0);
    __syncthreads();
  }

  const int row0 = (lane >> 4) * 4;
  const int col = lane & 15;
#pragma unroll
  for (int m = 0; m < 4; ++m) {
#pragma unroll
    for (int n = 0; n < 4; ++n) {
      int cn = bn + wn + n * 16 + col;
      float bv = bias[cn];
#pragma unroll
      for (int j = 0; j < 4; ++j) {
        int mg = bm + wm + m * 16 + row0 + j;
        if (mg < M) {
          float o = acc[m][n][j] + bv;
          if (OUTMODE == 2) o = fmaxf(o, 0.f);
          if (OUTMODE == 0) ((float*)Cv)[(size_t)mg * N + cn] = o;
          else ((ushort*)Cv)[(size_t)mg * N + cn] = f2b(o);
        }
      }
    }
  }
}

// ---------------------------------------------------------------------------
// Residual + LayerNorm (+ optional pos add), optional bf16 dual output.
// ---------------------------------------------------------------------------
__global__ __launch_bounds__(256) void ln_res(
    const float* __restrict__ X, const float* __restrict__ R,
    const float* __restrict__ G, const float* __restrict__ Bb,
    const float* __restrict__ POS, float* __restrict__ Y,
    ushort* __restrict__ Yb, int T) {
  int row = blockIdx.x * 4 + (threadIdx.x >> 6);
  int lane = threadIdx.x & 63;
  if (row >= T) return;
  size_t off = (size_t)row * 256 + lane * 4;
  float4 xv = *(const float4*)(X + off);
  float4 rv = *(const float4*)(R + off);
  float4 v = make_float4(xv.x + rv.x, xv.y + rv.y, xv.z + rv.z, xv.w + rv.w);
  float s = v.x + v.y + v.z + v.w;
#pragma unroll
  for (int o = 32; o; o >>= 1) s += __shfl_xor(s, o);
  float mu = s * (1.0f / 256.0f);
  float4 c = make_float4(v.x - mu, v.y - mu, v.z - mu, v.w - mu);
  float q = c.x * c.x + c.y * c.y + c.z * c.z + c.w * c.w;
#pragma unroll
  for (int o = 32; o; o >>= 1) q += __shfl_xor(q, o);
  float rs = rsqrtf(q * (1.0f / 256.0f) + 1e-5f);
  float4 g = *(const float4*)(G + lane * 4);
  float4 bb = *(const float4*)(Bb + lane * 4);
  float4 o4;
  o4.x = c.x * rs * g.x + bb.x;
  o4.y = c.y * rs * g.y + bb.y;
  o4.z = c.z * rs * g.z + bb.z;
  o4.w = c.w * rs * g.w + bb.w;
  if (POS) {
    float4 p = *(const float4*)(POS + off);
    o4.x += p.x; o4.y += p.y; o4.z += p.z; o4.w += p.w;
  }
  *(float4*)(Y + off) = o4;
  if (Yb) {
    ushort4 ob;
    ob.x = f2b(o4.x); ob.y = f2b(o4.y); ob.z = f2b(o4.z); ob.w = f2b(o4.w);
    *(ushort4*)(Yb + off) = ob;
  }
}

// ---------------------------------------------------------------------------
// Across-attention: S=100, B=144, token = s*144 + b. Output bf16.
// ---------------------------------------------------------------------------
__global__ __launch_bounds__(256) void attn_across(
    const float* __restrict__ QKV, ushort* __restrict__ O) {
  __shared__ float Qs[100][33];
  __shared__ float Ks[100][33];
  __shared__ float Vs[100][33];
  __shared__ float Ps[4][104];
  const int b = blockIdx.x >> 3, h = blockIdx.x & 7;
  const int tid = threadIdx.x;
  for (int idx = tid; idx < 100 * 32; idx += 256) {
    int r = idx >> 5, d = idx & 31;
    size_t base = ((size_t)r * 144 + b) * 768 + h * 32 + d;
    Qs[r][d] = QKV[base];
    Ks[r][d] = QKV[base + 256];
    Vs[r][d] = QKV[base + 512];
  }
  __syncthreads();
  const int wave = tid >> 6, lane = tid & 63;
  const float scale = 0.17677669529663687f;
  for (int s = wave; s < 100; s += 4) {
    float s0 = 0.f, s1 = 0.f;
    const int k1 = 64 + lane;
    const bool k1v = k1 < 100;
#pragma unroll 8
    for (int d = 0; d < 32; ++d) {
      float qd = Qs[s][d];
      s0 += qd * Ks[lane][d];
      s1 += qd * (k1v ? Ks[k1 & 127][d] : 0.f);
    }
    s0 *= scale;
    s1 = k1v ? s1 * scale : -1e30f;
    float mx = fmaxf(s0, s1);
#pragma unroll
    for (int o = 32; o; o >>= 1) mx = fmaxf(mx, __shfl_xor(mx, o));
    float e0 = __expf(s0 - mx);
    float e1 = k1v ? __expf(s1 - mx) : 0.f;
    float sum = e0 + e1;
#pragma unroll
    for (int o = 32; o; o >>= 1) sum += __shfl_xor(sum, o);
    float inv = 1.f / sum;
    Ps[wave][lane] = e0 * inv;
    if (lane < 40) Ps[wave][64 + lane] = (lane < 36) ? e1 * inv : 0.f;
    __syncthreads();
    int d = lane & 31, half2 = lane >> 5;
    float o = 0.f;
    int kb = half2 * 50;
    for (int k = kb; k < kb + 50; ++k) o += Ps[wave][k] * Vs[k][d];
    o += __shfl_xor(o, 32);
    if (lane < 32) O[((size_t)s * 144 + b) * 256 + h * 32 + d] = f2b(o);
    __syncthreads();
  }
}

// ---------------------------------------------------------------------------
// Within-attention: S=18, B=800, token = qq*144 + bb*18 + k. Output bf16.
// Uniform mask is softmax-invariant -> ignored.
// ---------------------------------------------------------------------------
__global__ __launch_bounds__(256) void attn_within(
    const float* __restrict__ QKV, ushort* __restrict__ O) {
  __shared__ float Qs[18 * 257];
  __shared__ float Ks[18 * 257];
  __shared__ float Vs[18 * 257];
  __shared__ float Ps[4][20];
  const int b = blockIdx.x;
  const int qq = b >> 3, bb = b & 7;
  const int tid = threadIdx.x;
  for (int idx = tid; idx < 18 * 256; idx += 256) {
    int r = idx >> 8, j = idx & 255;
    size_t tok = (size_t)qq * 144 + bb * 18 + r;
    size_t base = tok * 768 + j;
    Qs[r * 257 + j] = QKV[base];
    Ks[r * 257 + j] = QKV[base + 256];
    Vs[r * 257 + j] = QKV[base + 512];
  }
  __syncthreads();
  const int wave = tid >> 6, lane = tid & 63;
  const float scale = 0.17677669529663687f;
  for (int hh = 0; hh < 2; ++hh) {
    const int h = wave * 2 + hh;
    for (int s = 0; s < 18; ++s) {
      float sc = 0.f;
      const bool lv = lane < 18;
      const int lrow = lv ? lane : 0;
#pragma unroll 8
      for (int d = 0; d < 32; ++d) {
        sc += Qs[s * 257 + h * 32 + d] * Ks[lrow * 257 + h * 32 + d];
      }
      sc = lv ? sc * scale : -1e30f;
      float mx = sc;
#pragma unroll
      for (int o = 32; o; o >>= 1) mx = fmaxf(mx, __shfl_xor(mx, o));
      float e = lv ? __expf(sc - mx) : 0.f;
      float sum = e;
#pragma unroll
      for (int o = 32; o; o >>= 1) sum += __shfl_xor(sum, o);
      if (lv) Ps[wave][lane] = e / sum;
      __syncthreads();
      int d = lane & 31;
      float o = 0.f;
#pragma unroll
      for (int k = 0; k < 18; ++k) o += Ps[wave][k] * Vs[k * 257 + h * 32 + d];
      if (lane < 32) {
        size_t tok = (size_t)qq * 144 + bb * 18 + s;
        O[tok * 256 + h * 32 + d] = f2b(o);
      }
      __syncthreads();
    }
  }
}

// ---------------------------------------------------------------------------
// Deformable sampling: block per (b,lq); thread = (h,d). V is bf16.
// Output bf16 in token order.
// ---------------------------------------------------------------------------
__global__ __launch_bounds__(256) void deform_sample(
    const float* __restrict__ OFF, const float* __restrict__ AW,
    const ushort* __restrict__ V, const float* __restrict__ REF,
    ushort* __restrict__ OUT) {
  const int m = blockIdx.x;
  const int b = m / LQ_, lq = m - b * LQ_;
  const int qq = lq / NK_, kk = lq - qq * NK_;
  __shared__ float aw_sm[8][16];
  const int tid = threadIdx.x;
  if (tid < 128) {
    int h = tid >> 4, j = tid & 15;
    float v = AW[(size_t)m * 128 + h * 16 + j];
    float mx = v;
#pragma unroll
    for (int o = 8; o; o >>= 1) mx = fmaxf(mx, __shfl_xor(mx, o, 16));
    float e = __expf(v - mx);
    float sm = e;
#pragma unroll
    for (int o = 8; o; o >>= 1) sm += __shfl_xor(sm, o, 16);
    aw_sm[h][j] = e / sm;
  }
  __syncthreads();
  const int h = tid >> 5, d = tid & 31;
  const int WH[4] = {100, 50, 25, 13};
  const int ST[4] = {0, 10000, 12500, 13125};
  const size_t vbase = (size_t)b * LIN_;
  const int hd = h * 32 + d;
  float acc = 0.f;
#pragma unroll
  for (int li = 0; li < 4; ++li) {
    const int Wl = WH[li], Hl = WH[li], st = ST[li];
    const float fW = (float)Wl, fH = (float)Hl;
    float rx = REF[(((size_t)lq * 8 + b) * 4 + li) * 2 + 0];
    float ry = REF[(((size_t)lq * 8 + b) * 4 + li) * 2 + 1];
#pragma unroll
    for (int p = 0; p < 4; ++p) {
      float ox = OFF[(size_t)m * 256 + h * 32 + li * 8 + p * 2 + 0];
      float oy = OFF[(size_t)m * 256 + h * 32 + li * 8 + p * 2 + 1];
      float x = (rx + ox / fW) * fW - 0.5f;
      float y = (ry + oy / fH) * fH - 0.5f;
      float x0f = floorf(x), y0f = floorf(y);
      float lx = x - x0f, ly = y - y0f;
      int x0 = (int)x0f, y0 = (int)y0f;
      float a = aw_sm[h][li * 4 + p];
      float c00, c10, c01, c11;
      {
        int xi = x0, yi = y0;
        bool va = (xi >= 0) && (xi < Wl) && (yi >= 0) && (yi < Hl);
        int xc = min(max(xi, 0), Wl - 1), yc = min(max(yi, 0), Hl - 1);
        float v = b2f(V[(vbase + st + yc * Wl + xc) * 256 + hd]);
        c00 = va ? v : 0.f;
      }
      {
        int xi = x0 + 1, yi = y0;
        bool va = (xi >= 0) && (xi < Wl) && (yi >= 0) && (yi < Hl);
        int xc = min(max(xi, 0), Wl - 1), yc = min(max(yi, 0), Hl - 1);
        float v = b2f(V[(vbase + st + yc * Wl + xc) * 256 + hd]);
        c10 = va ? v : 0.f;
      }
      {
        int xi = x0, yi = y0 + 1;
        bool va = (xi >= 0) && (xi < Wl) && (yi >= 0) && (yi < Hl);
        int xc = min(max(xi, 0), Wl - 1), yc = min(max(yi, 0), Hl - 1);
        float v = b2f(V[(vbase + st + yc * Wl + xc) * 256 + hd]);
        c01 = va ? v : 0.f;
      }
      {
        int xi = x0 + 1, yi = y0 + 1;
        bool va = (xi >= 0) && (xi < Wl) && (yi >= 0) && (yi < Hl);
        int xc = min(max(xi, 0), Wl - 1), yc = min(max(yi, 0), Hl - 1);
        float v = b2f(V[(vbase + st + yc * Wl + xc) * 256 + hd]);
        c11 = va ? v : 0.f;
      }
      float bil = c00 * (1.f - lx) * (1.f - ly) + c10 * lx * (1.f - ly) +
                  c01 * (1.f - lx) * ly + c11 * lx * ly;
      acc += a * bil;
    }
  }
  size_t tok = (size_t)qq * 144 + b * 18 + kk;
  OUT[tok * 256 + hd] = f2b(acc);
}

// ---------------------------------------------------------------------------
extern "C" void kernel_launch(void* const* d_in, const int* in_sizes, int n_in,
                              void* d_out, int out_size, void* d_ws, size_t ws_size,
                              hipStream_t stream) {
  const float* tgt  = (const float*)d_in[0];
  const float* pos  = (const float*)d_in[1];
  const float* ref  = (const float*)d_in[2];
  const float* mem  = (const float*)d_in[3];
  const float* across_in_w  = (const float*)d_in[4];
  const float* across_in_b  = (const float*)d_in[5];
  const float* across_out_w = (const float*)d_in[6];
  const float* across_out_b = (const float*)d_in[7];
  const float* within_in_w  = (const float*)d_in[8];
  const float* within_in_b  = (const float*)d_in[9];
  const float* within_out_w = (const float*)d_in[10];
  const float* within_out_b = (const float*)d_in[11];
  const float* off_w  = (const float*)d_in[12];
  const float* off_b  = (const float*)d_in[13];
  const float* aw_w   = (const float*)d_in[14];
  const float* aw_b   = (const float*)d_in[15];
  const float* val_w  = (const float*)d_in[16];
  const float* val_b  = (const float*)d_in[17];
  const float* msout_w = (const float*)d_in[18];
  const float* msout_b = (const float*)d_in[19];
  const float* lin1_w  = (const float*)d_in[20];
  const float* lin1_b  = (const float*)d_in[21];
  const float* lin2_w  = (const float*)d_in[22];
  const float* lin2_b  = (const float*)d_in[23];
  const float* lin1p_w = (const float*)d_in[24];
  const float* lin1p_b = (const float*)d_in[25];
  const float* lin2p_w = (const float*)d_in[26];
  const float* lin2p_b = (const float*)d_in[27];
  const float* across_norm_g = (const float*)d_in[28];
  const float* across_norm_b = (const float*)d_in[29];
  const float* within_norm_g = (const float*)d_in[30];
  const float* within_norm_b = (const float*)d_in[31];
  const float* norm1_g = (const float*)d_in[32];
  const float* norm1_b = (const float*)d_in[33];
  const float* norm2_g = (const float*)d_in[34];
  const float* norm2_b = (const float*)d_in[35];
  const float* norm2p_g = (const float*)d_in[36];
  const float* norm2p_b = (const float*)d_in[37];

  // ---- workspace layout (bytes) ----
  char* w = (char*)d_ws;
  ushort* Wb  = (ushort*)w;                     w += 3604480;   // weights bf16
  float*  QKV = (float*)w;                      w += (size_t)T_ * 768 * 4;  // 44.2MB
  ushort* AOb = (ushort*)w;                     w += (size_t)T_ * 256 * 2;  // 7.37MB (also SMPb)
  float*  CT  = (float*)w;                      w += (size_t)T_ * 256 * 4;  // 14.7MB
  ushort* CTb = (ushort*)w;                     w += (size_t)T_ * 256 * 2;  // 7.37MB
  ushort* Vb  = (ushort*)w;                     w += (size_t)(BS_ * LIN_) * 256 * 2; // 54.5MB (also Uff)
  float*  OFFb = (float*)w;                     w += (size_t)T_ * 256 * 4;  // 14.7MB
  float*  AWw = (float*)w;                      w += (size_t)T_ * 128 * 4;  // 7.37MB
  ushort* Uff = Vb;      // FFN hidden reuses value-table region (disjoint lifetime)
  ushort* SMPb = AOb;    // deform output reuses attn-output region
  float*  Bt  = (float*)d_out;

  ushort* W_across_in  = Wb + WOF0;
  ushort* W_within_in  = Wb + WOF1;
  ushort* W_across_out = Wb + WOF2;
  ushort* W_within_out = Wb + WOF3;
  ushort* W_off        = Wb + WOF4;
  ushort* W_aw         = Wb + WOF5;
  ushort* W_val        = Wb + WOF6;
  ushort* W_msout      = Wb + WOF7;
  ushort* W_lin1       = Wb + WOF8;
  ushort* W_lin2       = Wb + WOF9;
  ushort* W_lin1p      = Wb + WOF10;
  ushort* W_lin2p      = Wb + WOF11;

  dim3 blk(256);
  const int MT = T_;                 // 14400
  const int MV = BS_ * LIN_;         // 106352
  const int MTt = (MT + 127) / 128;  // 113
  const int MVt = (MV + 127) / 128;  // 831
  dim3 gLN((MT + 3) / 4);

  // 0. weights -> bf16
  conv_weights<<<dim3((WTOT / 8 + 255) / 256), blk, 0, stream>>>(
      across_in_w, within_in_w, across_out_w, within_out_w, off_w, aw_w,
      val_w, msout_w, lin1_w, lin2_w, lin1p_w, lin2p_w, Wb);
  // 1. across in-proj (f32 A) -> QKV f32
  gemm_mfma<0, true, 0><<<dim3(6, MTt), blk, 0, stream>>>(
      tgt, W_across_in, across_in_b, QKV, MT, 768, 256);
  // 2. across attention -> AOb bf16
  attn_across<<<dim3(144 * 8), blk, 0, stream>>>(QKV, AOb);
  // 3. across out-proj -> Bt f32
  gemm_mfma<0, false, 0><<<dim3(2, MTt), blk, 0, stream>>>(
      AOb, W_across_out, across_out_b, Bt, MT, 256, 256);
  // 4. CT = LN(tgt + Bt) + pos  (f32 + bf16)
  ln_res<<<gLN, blk, 0, stream>>>(tgt, Bt, across_norm_g, across_norm_b, pos, CT, CTb, MT);
  // 5. value projection (f32 mem, AMODE1) -> Vb bf16
  gemm_mfma<1, true, 1><<<dim3(2, MVt), blk, 0, stream>>>(
      mem, W_val, val_b, Vb, MV, 256, 256);
  // 6. offsets (AMODE2) -> OFFb f32
  gemm_mfma<2, false, 0><<<dim3(2, MTt), blk, 0, stream>>>(
      CTb, W_off, off_b, OFFb, MT, 256, 256);
  // 7. attention weights (AMODE2) -> AWw f32
  gemm_mfma<2, false, 0><<<dim3(1, MTt), blk, 0, stream>>>(
      CTb, W_aw, aw_b, AWw, MT, 128, 256);
  // 8. bilinear sampling -> SMPb bf16 (token order)
  deform_sample<<<dim3(BS_ * LQ_), blk, 0, stream>>>(OFFb, AWw, Vb, ref, SMPb);
  // 9. msout -> Bt
  gemm_mfma<0, false, 0><<<dim3(2, MTt), blk, 0, stream>>>(
      SMPb, W_msout, msout_b, Bt, MT, 256, 256);
  // 10. norm1
  ln_res<<<gLN, blk, 0, stream>>>(CT, Bt, norm1_g, norm1_b, nullptr, CT, CTb, MT);
  // 11. lin1 (+relu) -> Uff bf16
  gemm_mfma<0, false, 2><<<dim3(8, MTt), blk, 0, stream>>>(
      CTb, W_lin1, lin1_b, Uff, MT, 1024, 256);
  // 12. lin2 -> Bt
  gemm_mfma<0, false, 0><<<dim3(2, MTt), blk, 0, stream>>>(
      Uff, W_lin2, lin2_b, Bt, MT, 256, 1024);
  // 13. norm2 + pos
  ln_res<<<gLN, blk, 0, stream>>>(CT, Bt, norm2_g, norm2_b, pos, CT, CTb, MT);
  // 14. within in-proj -> QKV f32
  gemm_mfma<0, false, 0><<<dim3(6, MTt), blk, 0, stream>>>(
      CTb, W_within_in, within_in_b, QKV, MT, 768, 256);
  // 15. within attention -> AOb bf16
  attn_within<<<dim3(NQ_ * BS_), blk, 0, stream>>>(QKV, AOb);
  // 16. within out-proj -> Bt
  gemm_mfma<0, false, 0><<<dim3(2, MTt), blk, 0, stream>>>(
      AOb, W_within_out, within_out_b, Bt, MT, 256, 256);
  // 17. within_norm
  ln_res<<<gLN, blk, 0, stream>>>(CT, Bt, within_norm_g, within_norm_b, nullptr, CT, CTb, MT);
  // 18. lin1p (+relu) -> Uff
  gemm_mfma<0, false, 2><<<dim3(8, MTt), blk, 0, stream>>>(
      CTb, W_lin1p, lin1p_b, Uff, MT, 1024, 256);
  // 19. lin2p -> Bt
  gemm_mfma<0, false, 0><<<dim3(2, MTt), blk, 0, stream>>>(
      Uff, W_lin2p, lin2p_b, Bt, MT, 256, 1024);
  // 20. final norm2p -> d_out (f32 only)
  ln_res<<<gLN, blk, 0, stream>>>(CT, Bt, norm2p_g, norm2p_b, nullptr, (float*)d_out, nullptr, MT);
}

// Round 4
// 556.379 us; speedup vs baseline: 2.8476x; 1.2948x over previous
//
#include <hip/hip_runtime.h>
#include <cstdint>
#include <cstddef>

constexpr int D_   = 256;
constexpr int NK_  = 18;
constexpr int NQ_  = 100;
constexpr int BS_  = 8;
constexpr int T_   = NQ_ * BS_ * NK_;   // 14400 tokens
constexpr int LIN_ = 13294;
constexpr int LQ_  = NQ_ * NK_;         // 1800

typedef __attribute__((ext_vector_type(8))) short bfv8;
typedef __attribute__((ext_vector_type(4))) float f32x4;

__device__ __forceinline__ ushort f2b(float f) {
  uint32_t u = __builtin_bit_cast(uint32_t, f);
  u += 0x7fffu + ((u >> 16) & 1u);
  return (ushort)(u >> 16);
}
__device__ __forceinline__ float b2f(ushort h) {
  uint32_t u = ((uint32_t)h) << 16;
  return __builtin_bit_cast(float, u);
}

// ---------------------------------------------------------------------------
// Weight conversion: all 12 GEMM weights f32 -> bf16 into one arena.
// ---------------------------------------------------------------------------
constexpr int WOF0  = 0;        // across_in_w 196608
constexpr int WOF1  = 196608;   // within_in_w 196608
constexpr int WOF2  = 393216;   // across_out_w 65536
constexpr int WOF3  = 458752;   // within_out_w 65536
constexpr int WOF4  = 524288;   // off_w 65536
constexpr int WOF5  = 589824;   // aw_w 32768
constexpr int WOF6  = 622592;   // val_w 65536
constexpr int WOF7  = 688128;   // msout_w 65536
constexpr int WOF8  = 753664;   // lin1_w 262144
constexpr int WOF9  = 1015808;  // lin2_w 262144
constexpr int WOF10 = 1277952;  // lin1p_w 262144
constexpr int WOF11 = 1540096;  // lin2p_w 262144
constexpr int WTOT  = 1802240;

__global__ __launch_bounds__(256) void conv_weights(
    const float* __restrict__ w0, const float* __restrict__ w1,
    const float* __restrict__ w2, const float* __restrict__ w3,
    const float* __restrict__ w4, const float* __restrict__ w5,
    const float* __restrict__ w6, const float* __restrict__ w7,
    const float* __restrict__ w8, const float* __restrict__ w9,
    const float* __restrict__ w10, const float* __restrict__ w11,
    ushort* __restrict__ out) {
  int i8 = (blockIdx.x * 256 + threadIdx.x) * 8;
  if (i8 >= WTOT) return;
  const float* src; int off;
  if      (i8 < WOF1)  { src = w0;  off = WOF0; }
  else if (i8 < WOF2)  { src = w1;  off = WOF1; }
  else if (i8 < WOF3)  { src = w2;  off = WOF2; }
  else if (i8 < WOF4)  { src = w3;  off = WOF3; }
  else if (i8 < WOF5)  { src = w4;  off = WOF4; }
  else if (i8 < WOF6)  { src = w5;  off = WOF5; }
  else if (i8 < WOF7)  { src = w6;  off = WOF6; }
  else if (i8 < WOF8)  { src = w7;  off = WOF7; }
  else if (i8 < WOF9)  { src = w8;  off = WOF8; }
  else if (i8 < WOF10) { src = w9;  off = WOF9; }
  else if (i8 < WOF11) { src = w10; off = WOF10; }
  else                 { src = w11; off = WOF11; }
  const float4 v0 = *(const float4*)(src + (i8 - off));
  const float4 v1 = *(const float4*)(src + (i8 - off) + 4);
  uint4 o;
  o.x = (uint)f2b(v0.x) | ((uint)f2b(v0.y) << 16);
  o.y = (uint)f2b(v0.z) | ((uint)f2b(v0.w) << 16);
  o.z = (uint)f2b(v1.x) | ((uint)f2b(v1.y) << 16);
  o.w = (uint)f2b(v1.z) | ((uint)f2b(v1.w) << 16);
  *(uint4*)(out + i8) = o;
}

// ---------------------------------------------------------------------------
// MFMA GEMM (unchanged structure from round 2).
// ---------------------------------------------------------------------------
template<int AMODE, bool AF32, int OUTMODE>
__global__ __launch_bounds__(256) void gemm_mfma(
    const void* __restrict__ Av, const ushort* __restrict__ W,
    const float* __restrict__ bias, void* __restrict__ Cv,
    int M, int N, int K) {
  __shared__ ushort As[128][40];
  __shared__ ushort Bs[128][40];
  const int tid = threadIdx.x;
  const int bm = blockIdx.y * 128, bn = blockIdx.x * 128;
  const int r = tid >> 1, hf = tid & 1;

  int gm = bm + r; if (gm >= M) gm = M - 1;
  int asrc;
  if (AMODE == 0) {
    asrc = gm;
  } else if (AMODE == 1) {
    int b = gm / LIN_, i = gm - b * LIN_;
    asrc = i * BS_ + b;
  } else {
    int b = gm / LQ_, lq = gm - b * LQ_;
    int qq = lq / NK_, kk = lq - qq * NK_;
    asrc = qq * (BS_ * NK_) + b * NK_ + kk;
  }
  const float*  Af = (const float*)Av;
  const ushort* Ab = (const ushort*)Av;
  const ushort* wrow = W + (size_t)(bn + r) * K;

  const int wave = tid >> 6, lane = tid & 63;
  const int wm = (wave >> 1) * 64, wn = (wave & 1) * 64;
  const int fr = lane & 15, fk = lane >> 4;

  f32x4 acc[4][4] = {};
  for (int k0 = 0; k0 < K; k0 += 32) {
    if (AF32) {
      const float* p = Af + (size_t)asrc * K + k0 + hf * 16;
      float4 v0 = *(const float4*)p;
      float4 v1 = *(const float4*)(p + 4);
      float4 v2 = *(const float4*)(p + 8);
      float4 v3 = *(const float4*)(p + 12);
      ushort* d = &As[r][hf * 16];
      d[0]  = f2b(v0.x); d[1]  = f2b(v0.y); d[2]  = f2b(v0.z); d[3]  = f2b(v0.w);
      d[4]  = f2b(v1.x); d[5]  = f2b(v1.y); d[6]  = f2b(v1.z); d[7]  = f2b(v1.w);
      d[8]  = f2b(v2.x); d[9]  = f2b(v2.y); d[10] = f2b(v2.z); d[11] = f2b(v2.w);
      d[12] = f2b(v3.x); d[13] = f2b(v3.y); d[14] = f2b(v3.z); d[15] = f2b(v3.w);
    } else {
      const ushort* p = Ab + (size_t)asrc * K + k0 + hf * 16;
      uint4 u0 = *(const uint4*)p;
      uint4 u1 = *(const uint4*)(p + 8);
      *(uint4*)&As[r][hf * 16] = u0;
      *(uint4*)&As[r][hf * 16 + 8] = u1;
    }
    {
      const ushort* p = wrow + k0 + hf * 16;
      uint4 u0 = *(const uint4*)p;
      uint4 u1 = *(const uint4*)(p + 8);
      *(uint4*)&Bs[r][hf * 16] = u0;
      *(uint4*)&Bs[r][hf * 16 + 8] = u1;
    }
    __syncthreads();
    bfv8 a[4], b[4];
#pragma unroll
    for (int m = 0; m < 4; ++m)
      a[m] = *(const bfv8*)&As[wm + m * 16 + fr][fk * 8];
#pragma unroll
    for (int n = 0; n < 4; ++n)
      b[n] = *(const bfv8*)&Bs[wn + n * 16 + fr][fk * 8];
#pragma unroll
    for (int m = 0; m < 4; ++m)
#pragma unroll
      for (int n = 0; n < 4; ++n)
        acc[m][n] = __builtin_amdgcn_mfma_f32_16x16x32_bf16(a[m], b[n], acc[m][n], 0, 0, 0);
    __syncthreads();
  }

  const int row0 = (lane >> 4) * 4;
  const int col = lane & 15;
#pragma unroll
  for (int m = 0; m < 4; ++m) {
#pragma unroll
    for (int n = 0; n < 4; ++n) {
      int cn = bn + wn + n * 16 + col;
      float bv = bias[cn];
#pragma unroll
      for (int j = 0; j < 4; ++j) {
        int mg = bm + wm + m * 16 + row0 + j;
        if (mg < M) {
          float o = acc[m][n][j] + bv;
          if (OUTMODE == 2) o = fmaxf(o, 0.f);
          if (OUTMODE == 0) ((float*)Cv)[(size_t)mg * N + cn] = o;
          else ((ushort*)Cv)[(size_t)mg * N + cn] = f2b(o);
        }
      }
    }
  }
}

// ---------------------------------------------------------------------------
// Residual + LayerNorm (+ optional pos add), optional bf16 dual output.
// ---------------------------------------------------------------------------
__global__ __launch_bounds__(256) void ln_res(
    const float* __restrict__ X, const float* __restrict__ R,
    const float* __restrict__ G, const float* __restrict__ Bb,
    const float* __restrict__ POS, float* __restrict__ Y,
    ushort* __restrict__ Yb, int T) {
  int row = blockIdx.x * 4 + (threadIdx.x >> 6);
  int lane = threadIdx.x & 63;
  if (row >= T) return;
  size_t off = (size_t)row * 256 + lane * 4;
  float4 xv = *(const float4*)(X + off);
  float4 rv = *(const float4*)(R + off);
  float4 v = make_float4(xv.x + rv.x, xv.y + rv.y, xv.z + rv.z, xv.w + rv.w);
  float s = v.x + v.y + v.z + v.w;
#pragma unroll
  for (int o = 32; o; o >>= 1) s += __shfl_xor(s, o);
  float mu = s * (1.0f / 256.0f);
  float4 c = make_float4(v.x - mu, v.y - mu, v.z - mu, v.w - mu);
  float q = c.x * c.x + c.y * c.y + c.z * c.z + c.w * c.w;
#pragma unroll
  for (int o = 32; o; o >>= 1) q += __shfl_xor(q, o);
  float rs = rsqrtf(q * (1.0f / 256.0f) + 1e-5f);
  float4 g = *(const float4*)(G + lane * 4);
  float4 bb = *(const float4*)(Bb + lane * 4);
  float4 o4;
  o4.x = c.x * rs * g.x + bb.x;
  o4.y = c.y * rs * g.y + bb.y;
  o4.z = c.z * rs * g.z + bb.z;
  o4.w = c.w * rs * g.w + bb.w;
  if (POS) {
    float4 p = *(const float4*)(POS + off);
    o4.x += p.x; o4.y += p.y; o4.z += p.z; o4.w += p.w;
  }
  *(float4*)(Y + off) = o4;
  if (Yb) {
    ushort4 ob;
    ob.x = f2b(o4.x); ob.y = f2b(o4.y); ob.z = f2b(o4.z); ob.w = f2b(o4.w);
    *(ushort4*)(Yb + off) = ob;
  }
}

// ---------------------------------------------------------------------------
// Across-attention via MFMA. One block per (b,h); S=100 padded to 112.
// QKV bf16 [tok][768], token = s*144 + b. Output bf16 token-major.
// Scores: 7x7 tiles of mfma_16x16x32_bf16; softmax in-register (C-layout:
// col=lane&15, row=(lane>>4)*4+j; 16-lane shfl_xor reduce); P bf16 in LDS;
// PV: 7x2x4 tiles with V transposed in LDS.
// ---------------------------------------------------------------------------
__global__ __launch_bounds__(256) void attn_across_mfma(
    const ushort* __restrict__ QKV, ushort* __restrict__ O) {
  __shared__ ushort Qs[112][40];
  __shared__ ushort Ks[112][40];
  __shared__ ushort Vt[32][136];
  __shared__ ushort Ps[112][136];
  const int b = blockIdx.x >> 3, h = blockIdx.x & 7;
  const int tid = threadIdx.x;

  // stage Q, K rows (zero-pad rows 100..111)
  for (int idx = tid; idx < 112 * 16; idx += 256) {
    int r = idx >> 4, du = (idx & 15) * 2;
    uint q = 0, k = 0;
    if (r < 100) {
      size_t base = ((size_t)r * 144 + b) * 768 + h * 32 + du;
      q = *(const uint*)(QKV + base);
      k = *(const uint*)(QKV + base + 256);
    }
    *(uint*)&Qs[r][du] = q;
    *(uint*)&Ks[r][du] = k;
  }
  // stage V transposed: Vt[d][s], zero-pad s in [100,128)
  for (int idx = tid; idx < 128 * 32; idx += 256) {
    int s = idx >> 5, d = idx & 31;
    ushort v = 0;
    if (s < 100) v = QKV[((size_t)s * 144 + b) * 768 + 512 + h * 32 + d];
    Vt[d][s] = v;
  }
  // zero P pad cols [112,128) (softmax writes only cols < 112)
  for (int idx = tid; idx < 112 * 8; idx += 256) {
    int r = idx >> 3, c = 112 + (idx & 7) * 2;
    *(uint*)&Ps[r][c] = 0;
  }
  __syncthreads();

  const int wave = tid >> 6, lane = tid & 63;
  const int fr = lane & 15, fk = lane >> 4;
  const float scale = 0.17677669529663687f;  // 1/sqrt(32)

  // phase 1: scores + softmax -> Ps
#pragma unroll
  for (int mi = 0; mi < 2; ++mi) {
    const int mt = wave + mi * 4;
    if (mt < 7) {
      bfv8 aq = *(const bfv8*)&Qs[mt * 16 + fr][fk * 8];
      f32x4 sacc[7];
#pragma unroll
      for (int nt = 0; nt < 7; ++nt) {
        bfv8 bk = *(const bfv8*)&Ks[nt * 16 + fr][fk * 8];
        f32x4 z = {0.f, 0.f, 0.f, 0.f};
        sacc[nt] = __builtin_amdgcn_mfma_f32_16x16x32_bf16(aq, bk, z, 0, 0, 0);
      }
      const bool maskc = (lane & 15) >= 4;  // cols 96+c >= 100 invalid
#pragma unroll
      for (int j = 0; j < 4; ++j) {
        float v[7];
        float mx = -1e30f;
#pragma unroll
        for (int nt = 0; nt < 7; ++nt) {
          float s = sacc[nt][j] * scale;
          if (nt == 6 && maskc) s = -1e30f;
          v[nt] = s;
          mx = fmaxf(mx, s);
        }
        mx = fmaxf(mx, __shfl_xor(mx, 1));
        mx = fmaxf(mx, __shfl_xor(mx, 2));
        mx = fmaxf(mx, __shfl_xor(mx, 4));
        mx = fmaxf(mx, __shfl_xor(mx, 8));
        float sum = 0.f;
#pragma unroll
        for (int nt = 0; nt < 7; ++nt) {
          v[nt] = __expf(v[nt] - mx);
          sum += v[nt];
        }
        sum += __shfl_xor(sum, 1);
        sum += __shfl_xor(sum, 2);
        sum += __shfl_xor(sum, 4);
        sum += __shfl_xor(sum, 8);
        float inv = 1.f / sum;
        int row = mt * 16 + (lane >> 4) * 4 + j;
#pragma unroll
        for (int nt = 0; nt < 7; ++nt)
          Ps[row][nt * 16 + (lane & 15)] = f2b(v[nt] * inv);
      }
    }
  }
  __syncthreads();

  // phase 2: O = P @ V^T
  f32x4 oacc[2][2] = {};
#pragma unroll
  for (int mi = 0; mi < 2; ++mi) {
    const int mt = wave + mi * 4;
    if (mt < 7) {
#pragma unroll
      for (int ks = 0; ks < 4; ++ks) {
        bfv8 ap = *(const bfv8*)&Ps[mt * 16 + fr][ks * 32 + fk * 8];
#pragma unroll
        for (int n = 0; n < 2; ++n) {
          bfv8 bv = *(const bfv8*)&Vt[n * 16 + fr][ks * 32 + fk * 8];
          oacc[mi][n] = __builtin_amdgcn_mfma_f32_16x16x32_bf16(ap, bv, oacc[mi][n], 0, 0, 0);
        }
      }
#pragma unroll
      for (int n = 0; n < 2; ++n) {
#pragma unroll
        for (int j = 0; j < 4; ++j) {
          int q = mt * 16 + (lane >> 4) * 4 + j;
          if (q < 100) {
            O[((size_t)q * 144 + b) * 256 + h * 32 + n * 16 + (lane & 15)] =
                f2b(oacc[mi][n][j]);
          }
        }
      }
    }
  }
}

// ---------------------------------------------------------------------------
// Within-attention, barrier-free compute: S=18, token = qq*144 + bb*18 + k.
// One block per b; each 32-lane half-wave owns one head (8 heads = 4 waves).
// Lanes = keys for scores; shfl_xor softmax in the half; __shfl(p,k) for PV.
// Uniform mask is softmax-invariant -> ignored.
// ---------------------------------------------------------------------------
__global__ __launch_bounds__(256) void attn_within(
    const ushort* __restrict__ QKV, ushort* __restrict__ O) {
  constexpr int ST = 258;
  __shared__ ushort Qs[18 * ST];
  __shared__ ushort Ks[18 * ST];
  __shared__ ushort Vs[18 * ST];
  const int bidx = blockIdx.x;
  const int qq = bidx >> 3, bb = bidx & 7;
  const int tid = threadIdx.x;
  for (int idx = tid; idx < 18 * 128; idx += 256) {
    int r = idx >> 7, j2 = (idx & 127) * 2;
    size_t base = ((size_t)qq * 144 + bb * 18 + r) * 768 + j2;
    *(uint*)&Qs[r * ST + j2] = *(const uint*)(QKV + base);
    *(uint*)&Ks[r * ST + j2] = *(const uint*)(QKV + base + 256);
    *(uint*)&Vs[r * ST + j2] = *(const uint*)(QKV + base + 512);
  }
  __syncthreads();
  const int wave = tid >> 6, lane = tid & 63;
  const int h = wave * 2 + (lane >> 5);  // head of this half-wave
  const int li = lane & 31;
  const int hd = h * 32;
  const float scale = 0.17677669529663687f;
  const bool kv = li < 18;
  for (int s = 0; s < 18; ++s) {
    float sc = 0.f;
    if (kv) {
      const ushort* qrow = &Qs[s * ST + hd];
      const ushort* krow = &Ks[li * ST + hd];
#pragma unroll 8
      for (int d = 0; d < 32; ++d) sc += b2f(qrow[d]) * b2f(krow[d]);
    }
    sc = kv ? sc * scale : -1e30f;
    float mx = sc;
    mx = fmaxf(mx, __shfl_xor(mx, 16));
    mx = fmaxf(mx, __shfl_xor(mx, 8));
    mx = fmaxf(mx, __shfl_xor(mx, 4));
    mx = fmaxf(mx, __shfl_xor(mx, 2));
    mx = fmaxf(mx, __shfl_xor(mx, 1));
    float e = kv ? __expf(sc - mx) : 0.f;
    float sum = e;
    sum += __shfl_xor(sum, 16);
    sum += __shfl_xor(sum, 8);
    sum += __shfl_xor(sum, 4);
    sum += __shfl_xor(sum, 2);
    sum += __shfl_xor(sum, 1);
    float p = e / sum;
    float o = 0.f;
    const int half = lane & 32;
#pragma unroll
    for (int k = 0; k < 18; ++k) {
      float pk = __shfl(p, half + k);
      o += pk * b2f(Vs[k * ST + hd + li]);
    }
    O[((size_t)qq * 144 + bb * 18 + s) * 256 + hd + li] = f2b(o);
  }
}

// ---------------------------------------------------------------------------
// Deformable sampling: block per (b,lq); thread = (h,d). V is bf16.
// ---------------------------------------------------------------------------
__global__ __launch_bounds__(256) void deform_sample(
    const float* __restrict__ OFF, const float* __restrict__ AW,
    const ushort* __restrict__ V, const float* __restrict__ REF,
    ushort* __restrict__ OUT) {
  const int m = blockIdx.x;
  const int b = m / LQ_, lq = m - b * LQ_;
  const int qq = lq / NK_, kk = lq - qq * NK_;
  __shared__ float aw_sm[8][16];
  const int tid = threadIdx.x;
  if (tid < 128) {
    int h = tid >> 4, j = tid & 15;
    float v = AW[(size_t)m * 128 + h * 16 + j];
    float mx = v;
#pragma unroll
    for (int o = 8; o; o >>= 1) mx = fmaxf(mx, __shfl_xor(mx, o, 16));
    float e = __expf(v - mx);
    float sm = e;
#pragma unroll
    for (int o = 8; o; o >>= 1) sm += __shfl_xor(sm, o, 16);
    aw_sm[h][j] = e / sm;
  }
  __syncthreads();
  const int h = tid >> 5, d = tid & 31;
  const int WH[4] = {100, 50, 25, 13};
  const int ST[4] = {0, 10000, 12500, 13125};
  const size_t vbase = (size_t)b * LIN_;
  const int hd = h * 32 + d;
  float acc = 0.f;
#pragma unroll
  for (int li = 0; li < 4; ++li) {
    const int Wl = WH[li], Hl = WH[li], st = ST[li];
    const float fW = (float)Wl, fH = (float)Hl;
    float rx = REF[(((size_t)lq * 8 + b) * 4 + li) * 2 + 0];
    float ry = REF[(((size_t)lq * 8 + b) * 4 + li) * 2 + 1];
#pragma unroll
    for (int p = 0; p < 4; ++p) {
      float ox = OFF[(size_t)m * 256 + h * 32 + li * 8 + p * 2 + 0];
      float oy = OFF[(size_t)m * 256 + h * 32 + li * 8 + p * 2 + 1];
      float x = (rx + ox / fW) * fW - 0.5f;
      float y = (ry + oy / fH) * fH - 0.5f;
      float x0f = floorf(x), y0f = floorf(y);
      float lx = x - x0f, ly = y - y0f;
      int x0 = (int)x0f, y0 = (int)y0f;
      float a = aw_sm[h][li * 4 + p];
      float c00, c10, c01, c11;
      {
        int xi = x0, yi = y0;
        bool va = (xi >= 0) && (xi < Wl) && (yi >= 0) && (yi < Hl);
        int xc = min(max(xi, 0), Wl - 1), yc = min(max(yi, 0), Hl - 1);
        float v = b2f(V[(vbase + st + yc * Wl + xc) * 256 + hd]);
        c00 = va ? v : 0.f;
      }
      {
        int xi = x0 + 1, yi = y0;
        bool va = (xi >= 0) && (xi < Wl) && (yi >= 0) && (yi < Hl);
        int xc = min(max(xi, 0), Wl - 1), yc = min(max(yi, 0), Hl - 1);
        float v = b2f(V[(vbase + st + yc * Wl + xc) * 256 + hd]);
        c10 = va ? v : 0.f;
      }
      {
        int xi = x0, yi = y0 + 1;
        bool va = (xi >= 0) && (xi < Wl) && (yi >= 0) && (yi < Hl);
        int xc = min(max(xi, 0), Wl - 1), yc = min(max(yi, 0), Hl - 1);
        float v = b2f(V[(vbase + st + yc * Wl + xc) * 256 + hd]);
        c01 = va ? v : 0.f;
      }
      {
        int xi = x0 + 1, yi = y0 + 1;
        bool va = (xi >= 0) && (xi < Wl) && (yi >= 0) && (yi < Hl);
        int xc = min(max(xi, 0), Wl - 1), yc = min(max(yi, 0), Hl - 1);
        float v = b2f(V[(vbase + st + yc * Wl + xc) * 256 + hd]);
        c11 = va ? v : 0.f;
      }
      float bil = c00 * (1.f - lx) * (1.f - ly) + c10 * lx * (1.f - ly) +
                  c01 * (1.f - lx) * ly + c11 * lx * ly;
      acc += a * bil;
    }
  }
  size_t tok = (size_t)qq * 144 + b * 18 + kk;
  OUT[tok * 256 + hd] = f2b(acc);
}

// ---------------------------------------------------------------------------
extern "C" void kernel_launch(void* const* d_in, const int* in_sizes, int n_in,
                              void* d_out, int out_size, void* d_ws, size_t ws_size,
                              hipStream_t stream) {
  const float* tgt  = (const float*)d_in[0];
  const float* pos  = (const float*)d_in[1];
  const float* ref  = (const float*)d_in[2];
  const float* mem  = (const float*)d_in[3];
  const float* across_in_w  = (const float*)d_in[4];
  const float* across_in_b  = (const float*)d_in[5];
  const float* across_out_w = (const float*)d_in[6];
  const float* across_out_b = (const float*)d_in[7];
  const float* within_in_w  = (const float*)d_in[8];
  const float* within_in_b  = (const float*)d_in[9];
  const float* within_out_w = (const float*)d_in[10];
  const float* within_out_b = (const float*)d_in[11];
  const float* off_w  = (const float*)d_in[12];
  const float* off_b  = (const float*)d_in[13];
  const float* aw_w   = (const float*)d_in[14];
  const float* aw_b   = (const float*)d_in[15];
  const float* val_w  = (const float*)d_in[16];
  const float* val_b  = (const float*)d_in[17];
  const float* msout_w = (const float*)d_in[18];
  const float* msout_b = (const float*)d_in[19];
  const float* lin1_w  = (const float*)d_in[20];
  const float* lin1_b  = (const float*)d_in[21];
  const float* lin2_w  = (const float*)d_in[22];
  const float* lin2_b  = (const float*)d_in[23];
  const float* lin1p_w = (const float*)d_in[24];
  const float* lin1p_b = (const float*)d_in[25];
  const float* lin2p_w = (const float*)d_in[26];
  const float* lin2p_b = (const float*)d_in[27];
  const float* across_norm_g = (const float*)d_in[28];
  const float* across_norm_b = (const float*)d_in[29];
  const float* within_norm_g = (const float*)d_in[30];
  const float* within_norm_b = (const float*)d_in[31];
  const float* norm1_g = (const float*)d_in[32];
  const float* norm1_b = (const float*)d_in[33];
  const float* norm2_g = (const float*)d_in[34];
  const float* norm2_b = (const float*)d_in[35];
  const float* norm2p_g = (const float*)d_in[36];
  const float* norm2p_b = (const float*)d_in[37];

  // ---- workspace layout ----
  char* w = (char*)d_ws;
  ushort* Wb   = (ushort*)w;   w += 3604480;                      // weights bf16
  ushort* QKVb = (ushort*)w;   w += (size_t)T_ * 768 * 2;         // 22.1MB
  ushort* AOb  = (ushort*)w;   w += (size_t)T_ * 256 * 2;         // 7.37MB (also SMPb)
  float*  CT   = (float*)w;    w += (size_t)T_ * 256 * 4;         // 14.7MB
  ushort* CTb  = (ushort*)w;   w += (size_t)T_ * 256 * 2;         // 7.37MB
  ushort* Vb   = (ushort*)w;   w += (size_t)(BS_ * LIN_) * 256 * 2; // 54.5MB (also Uff)
  float*  OFFb = (float*)w;    w += (size_t)T_ * 256 * 4;         // 14.7MB
  float*  AWw  = (float*)w;    w += (size_t)T_ * 128 * 4;         // 7.37MB
  ushort* Uff  = Vb;
  ushort* SMPb = AOb;
  float*  Bt   = (float*)d_out;

  ushort* W_across_in  = Wb + WOF0;
  ushort* W_within_in  = Wb + WOF1;
  ushort* W_across_out = Wb + WOF2;
  ushort* W_within_out = Wb + WOF3;
  ushort* W_off        = Wb + WOF4;
  ushort* W_aw         = Wb + WOF5;
  ushort* W_val        = Wb + WOF6;
  ushort* W_msout      = Wb + WOF7;
  ushort* W_lin1       = Wb + WOF8;
  ushort* W_lin2       = Wb + WOF9;
  ushort* W_lin1p      = Wb + WOF10;
  ushort* W_lin2p      = Wb + WOF11;

  dim3 blk(256);
  const int MT = T_;                 // 14400
  const int MV = BS_ * LIN_;         // 106352
  const int MTt = (MT + 127) / 128;  // 113
  const int MVt = (MV + 127) / 128;  // 831
  dim3 gLN((MT + 3) / 4);

  // 0. weights -> bf16
  conv_weights<<<dim3((WTOT / 8 + 255) / 256), blk, 0, stream>>>(
      across_in_w, within_in_w, across_out_w, within_out_w, off_w, aw_w,
      val_w, msout_w, lin1_w, lin2_w, lin1p_w, lin2p_w, Wb);
  // 1. across in-proj (f32 A) -> QKVb bf16
  gemm_mfma<0, true, 1><<<dim3(6, MTt), blk, 0, stream>>>(
      tgt, W_across_in, across_in_b, QKVb, MT, 768, 256);
  // 2. across attention (MFMA) -> AOb bf16
  attn_across_mfma<<<dim3(144 * 8), blk, 0, stream>>>(QKVb, AOb);
  // 3. across out-proj -> Bt f32
  gemm_mfma<0, false, 0><<<dim3(2, MTt), blk, 0, stream>>>(
      AOb, W_across_out, across_out_b, Bt, MT, 256, 256);
  // 4. CT = LN(tgt + Bt) + pos  (f32 + bf16)
  ln_res<<<gLN, blk, 0, stream>>>(tgt, Bt, across_norm_g, across_norm_b, pos, CT, CTb, MT);
  // 5. value projection -> Vb bf16
  gemm_mfma<1, true, 1><<<dim3(2, MVt), blk, 0, stream>>>(
      mem, W_val, val_b, Vb, MV, 256, 256);
  // 6. offsets (AMODE2) -> OFFb f32
  gemm_mfma<2, false, 0><<<dim3(2, MTt), blk, 0, stream>>>(
      CTb, W_off, off_b, OFFb, MT, 256, 256);
  // 7. attention weights (AMODE2) -> AWw f32
  gemm_mfma<2, false, 0><<<dim3(1, MTt), blk, 0, stream>>>(
      CTb, W_aw, aw_b, AWw, MT, 128, 256);
  // 8. bilinear sampling -> SMPb bf16 (token order)
  deform_sample<<<dim3(BS_ * LQ_), blk, 0, stream>>>(OFFb, AWw, Vb, ref, SMPb);
  // 9. msout -> Bt
  gemm_mfma<0, false, 0><<<dim3(2, MTt), blk, 0, stream>>>(
      SMPb, W_msout, msout_b, Bt, MT, 256, 256);
  // 10. norm1
  ln_res<<<gLN, blk, 0, stream>>>(CT, Bt, norm1_g, norm1_b, nullptr, CT, CTb, MT);
  // 11. lin1 (+relu) -> Uff bf16
  gemm_mfma<0, false, 2><<<dim3(8, MTt), blk, 0, stream>>>(
      CTb, W_lin1, lin1_b, Uff, MT, 1024, 256);
  // 12. lin2 -> Bt
  gemm_mfma<0, false, 0><<<dim3(2, MTt), blk, 0, stream>>>(
      Uff, W_lin2, lin2_b, Bt, MT, 256, 1024);
  // 13. norm2 + pos
  ln_res<<<gLN, blk, 0, stream>>>(CT, Bt, norm2_g, norm2_b, pos, CT, CTb, MT);
  // 14. within in-proj -> QKVb bf16
  gemm_mfma<0, false, 1><<<dim3(6, MTt), blk, 0, stream>>>(
      CTb, W_within_in, within_in_b, QKVb, MT, 768, 256);
  // 15. within attention -> AOb bf16
  attn_within<<<dim3(NQ_ * BS_), blk, 0, stream>>>(QKVb, AOb);
  // 16. within out-proj -> Bt
  gemm_mfma<0, false, 0><<<dim3(2, MTt), blk, 0, stream>>>(
      AOb, W_within_out, within_out_b, Bt, MT, 256, 256);
  // 17. within_norm
  ln_res<<<gLN, blk, 0, stream>>>(CT, Bt, within_norm_g, within_norm_b, nullptr, CT, CTb, MT);
  // 18. lin1p (+relu) -> Uff
  gemm_mfma<0, false, 2><<<dim3(8, MTt), blk, 0, stream>>>(
      CTb, W_lin1p, lin1p_b, Uff, MT, 1024, 256);
  // 19. lin2p -> Bt
  gemm_mfma<0, false, 0><<<dim3(2, MTt), blk, 0, stream>>>(
      Uff, W_lin2p, lin2p_b, Bt, MT, 256, 1024);
  // 20. final norm2p -> d_out (f32 only)
  ln_res<<<gLN, blk, 0, stream>>>(CT, Bt, norm2p_g, norm2p_b, nullptr, (float*)d_out, nullptr, MT);
}

// Round 7
// 475.493 us; speedup vs baseline: 3.3321x; 1.1701x over previous
//
#include <hip/hip_runtime.h>
#include <cstdint>
#include <cstddef>

constexpr int D_   = 256;
constexpr int NK_  = 18;
constexpr int NQ_  = 100;
constexpr int BS_  = 8;
constexpr int T_   = NQ_ * BS_ * NK_;   // 14400 tokens
constexpr int LIN_ = 13294;
constexpr int LQ_  = NQ_ * NK_;         // 1800

typedef __attribute__((ext_vector_type(8))) short bfv8;
typedef __attribute__((ext_vector_type(4))) float f32x4;

__device__ __forceinline__ ushort f2b(float f) {
  uint32_t u = __builtin_bit_cast(uint32_t, f);
  u += 0x7fffu + ((u >> 16) & 1u);
  return (ushort)(u >> 16);
}
__device__ __forceinline__ float b2f(ushort h) {
  uint32_t u = ((uint32_t)h) << 16;
  return __builtin_bit_cast(float, u);
}

// ---------------------------------------------------------------------------
// Weight conversion: all 12 GEMM weights f32 -> bf16 into one arena.
// off_w (WOF4) and aw_w (WOF5) are adjacent -> fused N=384 GEMM reads them
// as one [384][256] weight matrix.
// ---------------------------------------------------------------------------
constexpr int WOF0  = 0;        // across_in_w 196608
constexpr int WOF1  = 196608;   // within_in_w 196608
constexpr int WOF2  = 393216;   // across_out_w 65536
constexpr int WOF3  = 458752;   // within_out_w 65536
constexpr int WOF4  = 524288;   // off_w 65536
constexpr int WOF5  = 589824;   // aw_w 32768
constexpr int WOF6  = 622592;   // val_w 65536
constexpr int WOF7  = 688128;   // msout_w 65536
constexpr int WOF8  = 753664;   // lin1_w 262144
constexpr int WOF9  = 1015808;  // lin2_w 262144
constexpr int WOF10 = 1277952;  // lin1p_w 262144
constexpr int WOF11 = 1540096;  // lin2p_w 262144
constexpr int WTOT  = 1802240;

__global__ __launch_bounds__(256) void conv_weights(
    const float* __restrict__ w0, const float* __restrict__ w1,
    const float* __restrict__ w2, const float* __restrict__ w3,
    const float* __restrict__ w4, const float* __restrict__ w5,
    const float* __restrict__ w6, const float* __restrict__ w7,
    const float* __restrict__ w8, const float* __restrict__ w9,
    const float* __restrict__ w10, const float* __restrict__ w11,
    ushort* __restrict__ out) {
  int i8 = (blockIdx.x * 256 + threadIdx.x) * 8;
  if (i8 >= WTOT) return;
  const float* src; int off;
  if      (i8 < WOF1)  { src = w0;  off = WOF0; }
  else if (i8 < WOF2)  { src = w1;  off = WOF1; }
  else if (i8 < WOF3)  { src = w2;  off = WOF2; }
  else if (i8 < WOF4)  { src = w3;  off = WOF3; }
  else if (i8 < WOF5)  { src = w4;  off = WOF4; }
  else if (i8 < WOF6)  { src = w5;  off = WOF5; }
  else if (i8 < WOF7)  { src = w6;  off = WOF6; }
  else if (i8 < WOF8)  { src = w7;  off = WOF7; }
  else if (i8 < WOF9)  { src = w8;  off = WOF8; }
  else if (i8 < WOF10) { src = w9;  off = WOF9; }
  else if (i8 < WOF11) { src = w10; off = WOF10; }
  else                 { src = w11; off = WOF11; }
  const float4 v0 = *(const float4*)(src + (i8 - off));
  const float4 v1 = *(const float4*)(src + (i8 - off) + 4);
  uint4 o;
  o.x = (uint)f2b(v0.x) | ((uint)f2b(v0.y) << 16);
  o.y = (uint)f2b(v0.z) | ((uint)f2b(v0.w) << 16);
  o.z = (uint)f2b(v1.x) | ((uint)f2b(v1.y) << 16);
  o.w = (uint)f2b(v1.z) | ((uint)f2b(v1.w) << 16);
  *(uint4*)(out + i8) = o;
}

// Pack off_b (256) + aw_b (128) into one 384-entry bias vector.
__global__ __launch_bounds__(384) void pack_bias(
    const float* __restrict__ off_b, const float* __restrict__ aw_b,
    float* __restrict__ out) {
  int t = threadIdx.x;
  out[t] = (t < 256) ? off_b[t] : aw_b[t - 256];
}

// ---------------------------------------------------------------------------
// MFMA GEMM (unchanged structure).
// ---------------------------------------------------------------------------
template<int AMODE, bool AF32, int OUTMODE>
__global__ __launch_bounds__(256) void gemm_mfma(
    const void* __restrict__ Av, const ushort* __restrict__ W,
    const float* __restrict__ bias, void* __restrict__ Cv,
    int M, int N, int K) {
  __shared__ ushort As[128][40];
  __shared__ ushort Bs[128][40];
  const int tid = threadIdx.x;
  const int bm = blockIdx.y * 128, bn = blockIdx.x * 128;
  const int r = tid >> 1, hf = tid & 1;

  int gm = bm + r; if (gm >= M) gm = M - 1;
  int asrc;
  if (AMODE == 0) {
    asrc = gm;
  } else if (AMODE == 1) {
    int b = gm / LIN_, i = gm - b * LIN_;
    asrc = i * BS_ + b;
  } else {
    int b = gm / LQ_, lq = gm - b * LQ_;
    int qq = lq / NK_, kk = lq - qq * NK_;
    asrc = qq * (BS_ * NK_) + b * NK_ + kk;
  }
  const float*  Af = (const float*)Av;
  const ushort* Ab = (const ushort*)Av;
  const ushort* wrow = W + (size_t)(bn + r) * K;

  const int wave = tid >> 6, lane = tid & 63;
  const int wm = (wave >> 1) * 64, wn = (wave & 1) * 64;
  const int fr = lane & 15, fk = lane >> 4;

  f32x4 acc[4][4] = {};
  for (int k0 = 0; k0 < K; k0 += 32) {
    if (AF32) {
      const float* p = Af + (size_t)asrc * K + k0 + hf * 16;
      float4 v0 = *(const float4*)p;
      float4 v1 = *(const float4*)(p + 4);
      float4 v2 = *(const float4*)(p + 8);
      float4 v3 = *(const float4*)(p + 12);
      ushort* d = &As[r][hf * 16];
      d[0]  = f2b(v0.x); d[1]  = f2b(v0.y); d[2]  = f2b(v0.z); d[3]  = f2b(v0.w);
      d[4]  = f2b(v1.x); d[5]  = f2b(v1.y); d[6]  = f2b(v1.z); d[7]  = f2b(v1.w);
      d[8]  = f2b(v2.x); d[9]  = f2b(v2.y); d[10] = f2b(v2.z); d[11] = f2b(v2.w);
      d[12] = f2b(v3.x); d[13] = f2b(v3.y); d[14] = f2b(v3.z); d[15] = f2b(v3.w);
    } else {
      const ushort* p = Ab + (size_t)asrc * K + k0 + hf * 16;
      uint4 u0 = *(const uint4*)p;
      uint4 u1 = *(const uint4*)(p + 8);
      *(uint4*)&As[r][hf * 16] = u0;
      *(uint4*)&As[r][hf * 16 + 8] = u1;
    }
    {
      const ushort* p = wrow + k0 + hf * 16;
      uint4 u0 = *(const uint4*)p;
      uint4 u1 = *(const uint4*)(p + 8);
      *(uint4*)&Bs[r][hf * 16] = u0;
      *(uint4*)&Bs[r][hf * 16 + 8] = u1;
    }
    __syncthreads();
    bfv8 a[4], b[4];
#pragma unroll
    for (int m = 0; m < 4; ++m)
      a[m] = *(const bfv8*)&As[wm + m * 16 + fr][fk * 8];
#pragma unroll
    for (int n = 0; n < 4; ++n)
      b[n] = *(const bfv8*)&Bs[wn + n * 16 + fr][fk * 8];
#pragma unroll
    for (int m = 0; m < 4; ++m)
#pragma unroll
      for (int n = 0; n < 4; ++n)
        acc[m][n] = __builtin_amdgcn_mfma_f32_16x16x32_bf16(a[m], b[n], acc[m][n], 0, 0, 0);
    __syncthreads();
  }

  const int row0 = (lane >> 4) * 4;
  const int col = lane & 15;
#pragma unroll
  for (int m = 0; m < 4; ++m) {
#pragma unroll
    for (int n = 0; n < 4; ++n) {
      int cn = bn + wn + n * 16 + col;
      float bv = bias[cn];
#pragma unroll
      for (int j = 0; j < 4; ++j) {
        int mg = bm + wm + m * 16 + row0 + j;
        if (mg < M) {
          float o = acc[m][n][j] + bv;
          if (OUTMODE == 2) o = fmaxf(o, 0.f);
          if (OUTMODE == 0) ((float*)Cv)[(size_t)mg * N + cn] = o;
          else ((ushort*)Cv)[(size_t)mg * N + cn] = f2b(o);
        }
      }
    }
  }
}

// ---------------------------------------------------------------------------
// Residual + LayerNorm (+ optional pos add), optional bf16 dual output.
// ---------------------------------------------------------------------------
__global__ __launch_bounds__(256) void ln_res(
    const float* __restrict__ X, const float* __restrict__ R,
    const float* __restrict__ G, const float* __restrict__ Bb,
    const float* __restrict__ POS, float* __restrict__ Y,
    ushort* __restrict__ Yb, int T) {
  int row = blockIdx.x * 4 + (threadIdx.x >> 6);
  int lane = threadIdx.x & 63;
  if (row >= T) return;
  size_t off = (size_t)row * 256 + lane * 4;
  float4 xv = *(const float4*)(X + off);
  float4 rv = *(const float4*)(R + off);
  float4 v = make_float4(xv.x + rv.x, xv.y + rv.y, xv.z + rv.z, xv.w + rv.w);
  float s = v.x + v.y + v.z + v.w;
#pragma unroll
  for (int o = 32; o; o >>= 1) s += __shfl_xor(s, o);
  float mu = s * (1.0f / 256.0f);
  float4 c = make_float4(v.x - mu, v.y - mu, v.z - mu, v.w - mu);
  float q = c.x * c.x + c.y * c.y + c.z * c.z + c.w * c.w;
#pragma unroll
  for (int o = 32; o; o >>= 1) q += __shfl_xor(q, o);
  float rs = rsqrtf(q * (1.0f / 256.0f) + 1e-5f);
  float4 g = *(const float4*)(G + lane * 4);
  float4 bb = *(const float4*)(Bb + lane * 4);
  float4 o4;
  o4.x = c.x * rs * g.x + bb.x;
  o4.y = c.y * rs * g.y + bb.y;
  o4.z = c.z * rs * g.z + bb.z;
  o4.w = c.w * rs * g.w + bb.w;
  if (POS) {
    float4 p = *(const float4*)(POS + off);
    o4.x += p.x; o4.y += p.y; o4.z += p.z; o4.w += p.w;
  }
  *(float4*)(Y + off) = o4;
  if (Yb) {
    ushort4 ob;
    ob.x = f2b(o4.x); ob.y = f2b(o4.y); ob.z = f2b(o4.z); ob.w = f2b(o4.w);
    *(ushort4*)(Yb + off) = ob;
  }
}

// ---------------------------------------------------------------------------
// Across-attention via MFMA (unchanged from round 2/3).
// ---------------------------------------------------------------------------
__global__ __launch_bounds__(256) void attn_across_mfma(
    const ushort* __restrict__ QKV, ushort* __restrict__ O) {
  __shared__ ushort Qs[112][40];
  __shared__ ushort Ks[112][40];
  __shared__ ushort Vt[32][136];
  __shared__ ushort Ps[112][136];
  const int b = blockIdx.x >> 3, h = blockIdx.x & 7;
  const int tid = threadIdx.x;

  for (int idx = tid; idx < 112 * 16; idx += 256) {
    int r = idx >> 4, du = (idx & 15) * 2;
    uint q = 0, k = 0;
    if (r < 100) {
      size_t base = ((size_t)r * 144 + b) * 768 + h * 32 + du;
      q = *(const uint*)(QKV + base);
      k = *(const uint*)(QKV + base + 256);
    }
    *(uint*)&Qs[r][du] = q;
    *(uint*)&Ks[r][du] = k;
  }
  for (int idx = tid; idx < 128 * 32; idx += 256) {
    int s = idx >> 5, d = idx & 31;
    ushort v = 0;
    if (s < 100) v = QKV[((size_t)s * 144 + b) * 768 + 512 + h * 32 + d];
    Vt[d][s] = v;
  }
  for (int idx = tid; idx < 112 * 8; idx += 256) {
    int r = idx >> 3, c = 112 + (idx & 7) * 2;
    *(uint*)&Ps[r][c] = 0;
  }
  __syncthreads();

  const int wave = tid >> 6, lane = tid & 63;
  const int fr = lane & 15, fk = lane >> 4;
  const float scale = 0.17677669529663687f;

#pragma unroll
  for (int mi = 0; mi < 2; ++mi) {
    const int mt = wave + mi * 4;
    if (mt < 7) {
      bfv8 aq = *(const bfv8*)&Qs[mt * 16 + fr][fk * 8];
      f32x4 sacc[7];
#pragma unroll
      for (int nt = 0; nt < 7; ++nt) {
        bfv8 bk = *(const bfv8*)&Ks[nt * 16 + fr][fk * 8];
        f32x4 z = {0.f, 0.f, 0.f, 0.f};
        sacc[nt] = __builtin_amdgcn_mfma_f32_16x16x32_bf16(aq, bk, z, 0, 0, 0);
      }
      const bool maskc = (lane & 15) >= 4;
#pragma unroll
      for (int j = 0; j < 4; ++j) {
        float v[7];
        float mx = -1e30f;
#pragma unroll
        for (int nt = 0; nt < 7; ++nt) {
          float s = sacc[nt][j] * scale;
          if (nt == 6 && maskc) s = -1e30f;
          v[nt] = s;
          mx = fmaxf(mx, s);
        }
        mx = fmaxf(mx, __shfl_xor(mx, 1));
        mx = fmaxf(mx, __shfl_xor(mx, 2));
        mx = fmaxf(mx, __shfl_xor(mx, 4));
        mx = fmaxf(mx, __shfl_xor(mx, 8));
        float sum = 0.f;
#pragma unroll
        for (int nt = 0; nt < 7; ++nt) {
          v[nt] = __expf(v[nt] - mx);
          sum += v[nt];
        }
        sum += __shfl_xor(sum, 1);
        sum += __shfl_xor(sum, 2);
        sum += __shfl_xor(sum, 4);
        sum += __shfl_xor(sum, 8);
        float inv = 1.f / sum;
        int row = mt * 16 + (lane >> 4) * 4 + j;
#pragma unroll
        for (int nt = 0; nt < 7; ++nt)
          Ps[row][nt * 16 + (lane & 15)] = f2b(v[nt] * inv);
      }
    }
  }
  __syncthreads();

  f32x4 oacc[2][2] = {};
#pragma unroll
  for (int mi = 0; mi < 2; ++mi) {
    const int mt = wave + mi * 4;
    if (mt < 7) {
#pragma unroll
      for (int ks = 0; ks < 4; ++ks) {
        bfv8 ap = *(const bfv8*)&Ps[mt * 16 + fr][ks * 32 + fk * 8];
#pragma unroll
        for (int n = 0; n < 2; ++n) {
          bfv8 bv = *(const bfv8*)&Vt[n * 16 + fr][ks * 32 + fk * 8];
          oacc[mi][n] = __builtin_amdgcn_mfma_f32_16x16x32_bf16(ap, bv, oacc[mi][n], 0, 0, 0);
        }
      }
#pragma unroll
      for (int n = 0; n < 2; ++n) {
#pragma unroll
        for (int j = 0; j < 4; ++j) {
          int q = mt * 16 + (lane >> 4) * 4 + j;
          if (q < 100) {
            O[((size_t)q * 144 + b) * 256 + h * 32 + n * 16 + (lane & 15)] =
                f2b(oacc[mi][n][j]);
          }
        }
      }
    }
  }
}

// ---------------------------------------------------------------------------
// Within-attention (unchanged from round 2/3).
// ---------------------------------------------------------------------------
__global__ __launch_bounds__(256) void attn_within(
    const ushort* __restrict__ QKV, ushort* __restrict__ O) {
  constexpr int ST = 258;
  __shared__ ushort Qs[18 * ST];
  __shared__ ushort Ks[18 * ST];
  __shared__ ushort Vs[18 * ST];
  const int bidx = blockIdx.x;
  const int qq = bidx >> 3, bb = bidx & 7;
  const int tid = threadIdx.x;
  for (int idx = tid; idx < 18 * 128; idx += 256) {
    int r = idx >> 7, j2 = (idx & 127) * 2;
    size_t base = ((size_t)qq * 144 + bb * 18 + r) * 768 + j2;
    *(uint*)&Qs[r * ST + j2] = *(const uint*)(QKV + base);
    *(uint*)&Ks[r * ST + j2] = *(const uint*)(QKV + base + 256);
    *(uint*)&Vs[r * ST + j2] = *(const uint*)(QKV + base + 512);
  }
  __syncthreads();
  const int wave = tid >> 6, lane = tid & 63;
  const int h = wave * 2 + (lane >> 5);
  const int li = lane & 31;
  const int hd = h * 32;
  const float scale = 0.17677669529663687f;
  const bool kv = li < 18;
  for (int s = 0; s < 18; ++s) {
    float sc = 0.f;
    if (kv) {
      const ushort* qrow = &Qs[s * ST + hd];
      const ushort* krow = &Ks[li * ST + hd];
#pragma unroll 8
      for (int d = 0; d < 32; ++d) sc += b2f(qrow[d]) * b2f(krow[d]);
    }
    sc = kv ? sc * scale : -1e30f;
    float mx = sc;
    mx = fmaxf(mx, __shfl_xor(mx, 16));
    mx = fmaxf(mx, __shfl_xor(mx, 8));
    mx = fmaxf(mx, __shfl_xor(mx, 4));
    mx = fmaxf(mx, __shfl_xor(mx, 2));
    mx = fmaxf(mx, __shfl_xor(mx, 1));
    float e = kv ? __expf(sc - mx) : 0.f;
    float sum = e;
    sum += __shfl_xor(sum, 16);
    sum += __shfl_xor(sum, 8);
    sum += __shfl_xor(sum, 4);
    sum += __shfl_xor(sum, 2);
    sum += __shfl_xor(sum, 1);
    float p = e / sum;
    float o = 0.f;
    const int half = lane & 32;
#pragma unroll
    for (int k = 0; k < 18; ++k) {
      float pk = __shfl(p, half + k);
      o += pk * b2f(Vs[k * ST + hd + li]);
    }
    O[((size_t)qq * 144 + bb * 18 + s) * 256 + hd + li] = f2b(o);
  }
}

// ---------------------------------------------------------------------------
// Deformable sampling, two-phase, 4 queries/block (grid 3600).
// Phase 1: 512 sample descriptors (4q x 8h x 16lp) computed ONCE each:
//   4 corner (clamped idx, weight) pairs in LDS (weight = softmax(aw) *
//   bilinear * validity).  Softmax over lp via 16-lane shfl.
// Phase 2: one wave per query; thread = (h, d-group of 4); ushort4 gathers
//   with LDS-broadcast weights.  LDS layout skewed per (g,h) to decluster
//   the 512B stride.
// OFFAW: [m][384] f32 (256 off + 128 aw), m = b*1800+lq.
// ---------------------------------------------------------------------------
__global__ __launch_bounds__(256) void deform_sample(
    const float* __restrict__ OFFAW, const ushort* __restrict__ V,
    const float* __restrict__ REF, ushort* __restrict__ OUT) {
  __shared__ uint2 sDesc[32 * 65];  // (g*8+h)*65 + lp*4 + c
  const int tid = threadIdx.x;
  const int m0 = blockIdx.x * 4;

  const int WH[4] = {100, 50, 25, 13};
  const int STl[4] = {0, 10000, 12500, 13125};

  // ---- phase 1: two descriptors per thread ----
#pragma unroll
  for (int dd = 0; dd < 2; ++dd) {
    const int desc = tid + dd * 256;
    const int g = desc >> 7, rem = desc & 127;
    const int h = rem >> 4, lp = rem & 15, li = lp >> 2, p = lp & 3;
    const int m = m0 + g;
    const int b = m / LQ_, lq = m - b * LQ_;

    // softmax over the 16 lp values of this (g,h)
    float awv = OFFAW[(size_t)m * 384 + 256 + h * 16 + lp];
    float mx = awv;
    mx = fmaxf(mx, __shfl_xor(mx, 8, 16));
    mx = fmaxf(mx, __shfl_xor(mx, 4, 16));
    mx = fmaxf(mx, __shfl_xor(mx, 2, 16));
    mx = fmaxf(mx, __shfl_xor(mx, 1, 16));
    float e = __expf(awv - mx);
    float sm = e;
    sm += __shfl_xor(sm, 8, 16);
    sm += __shfl_xor(sm, 4, 16);
    sm += __shfl_xor(sm, 2, 16);
    sm += __shfl_xor(sm, 1, 16);
    const float aw = e / sm;

    const float* offp = OFFAW + (size_t)m * 384 + h * 32 + li * 8 + p * 2;
    const float ox = offp[0], oy = offp[1];
    const float rx = REF[(((size_t)lq * 8 + b) * 4 + li) * 2 + 0];
    const float ry = REF[(((size_t)lq * 8 + b) * 4 + li) * 2 + 1];
    const int Wl = WH[li], st = STl[li];
    const float fW = (float)Wl;
    const float x = fmaf(rx, fW, ox) - 0.5f;
    const float y = fmaf(ry, fW, oy) - 0.5f;
    const float x0f = floorf(x), y0f = floorf(y);
    const float lx = x - x0f, ly = y - y0f;
    const int x0 = (int)x0f, y0 = (int)y0f;
    const int base = (g * 8 + h) * 65 + lp * 4;
#pragma unroll
    for (int c = 0; c < 4; ++c) {
      const int cx = c & 1, cy = c >> 1;
      const int xi = x0 + cx, yi = y0 + cy;
      const bool va = (xi >= 0) && (xi < Wl) && (yi >= 0) && (yi < Wl);
      const int xc = min(max(xi, 0), Wl - 1);
      const int yc = min(max(yi, 0), Wl - 1);
      const float wx = cx ? lx : (1.f - lx);
      const float wy = cy ? ly : (1.f - ly);
      const float wgt = va ? aw * wx * wy : 0.f;
      uint2 dv;
      dv.x = (uint)(st + yc * Wl + xc);
      dv.y = __builtin_bit_cast(uint, wgt);
      sDesc[base + c] = dv;
    }
  }
  __syncthreads();

  // ---- phase 2: gather + accumulate; one wave per query ----
  const int g = tid >> 6;
  const int h = (tid >> 3) & 7;
  const int d4 = (tid & 7) * 4;
  const int m = m0 + g;
  const int b = m / LQ_, lq = m - b * LQ_;
  const int qq = lq / NK_, kk = lq - qq * NK_;
  const ushort* Vg = V + ((size_t)b * LIN_) * 256 + h * 32 + d4;
  const int dbase = (g * 8 + h) * 65;
  float a0 = 0.f, a1 = 0.f, a2 = 0.f, a3 = 0.f;
#pragma unroll
  for (int lp = 0; lp < 16; ++lp) {
#pragma unroll
    for (int c = 0; c < 4; ++c) {
      const uint2 dv = sDesc[dbase + lp * 4 + c];
      const float w = __builtin_bit_cast(float, dv.y);
      const ushort4 v = *(const ushort4*)(Vg + (size_t)dv.x * 256);
      a0 = fmaf(w, b2f(v.x), a0);
      a1 = fmaf(w, b2f(v.y), a1);
      a2 = fmaf(w, b2f(v.z), a2);
      a3 = fmaf(w, b2f(v.w), a3);
    }
  }
  const size_t tok = (size_t)qq * 144 + b * 18 + kk;
  ushort4 o;
  o.x = f2b(a0); o.y = f2b(a1); o.z = f2b(a2); o.w = f2b(a3);
  *(ushort4*)(OUT + tok * 256 + h * 32 + d4) = o;
}

// ---------------------------------------------------------------------------
extern "C" void kernel_launch(void* const* d_in, const int* in_sizes, int n_in,
                              void* d_out, int out_size, void* d_ws, size_t ws_size,
                              hipStream_t stream) {
  const float* tgt  = (const float*)d_in[0];
  const float* pos  = (const float*)d_in[1];
  const float* ref  = (const float*)d_in[2];
  const float* mem  = (const float*)d_in[3];
  const float* across_in_w  = (const float*)d_in[4];
  const float* across_in_b  = (const float*)d_in[5];
  const float* across_out_w = (const float*)d_in[6];
  const float* across_out_b = (const float*)d_in[7];
  const float* within_in_w  = (const float*)d_in[8];
  const float* within_in_b  = (const float*)d_in[9];
  const float* within_out_w = (const float*)d_in[10];
  const float* within_out_b = (const float*)d_in[11];
  const float* off_w  = (const float*)d_in[12];
  const float* off_b  = (const float*)d_in[13];
  const float* aw_w   = (const float*)d_in[14];
  const float* aw_b   = (const float*)d_in[15];
  const float* val_w  = (const float*)d_in[16];
  const float* val_b  = (const float*)d_in[17];
  const float* msout_w = (const float*)d_in[18];
  const float* msout_b = (const float*)d_in[19];
  const float* lin1_w  = (const float*)d_in[20];
  const float* lin1_b  = (const float*)d_in[21];
  const float* lin2_w  = (const float*)d_in[22];
  const float* lin2_b  = (const float*)d_in[23];
  const float* lin1p_w = (const float*)d_in[24];
  const float* lin1p_b = (const float*)d_in[25];
  const float* lin2p_w = (const float*)d_in[26];
  const float* lin2p_b = (const float*)d_in[27];
  const float* across_norm_g = (const float*)d_in[28];
  const float* across_norm_b = (const float*)d_in[29];
  const float* within_norm_g = (const float*)d_in[30];
  const float* within_norm_b = (const float*)d_in[31];
  const float* norm1_g = (const float*)d_in[32];
  const float* norm1_b = (const float*)d_in[33];
  const float* norm2_g = (const float*)d_in[34];
  const float* norm2_b = (const float*)d_in[35];
  const float* norm2p_g = (const float*)d_in[36];
  const float* norm2p_b = (const float*)d_in[37];

  // ---- workspace layout ----
  char* w = (char*)d_ws;
  ushort* Wb    = (ushort*)w;  w += 3604480;                        // weights bf16
  ushort* QKVb  = (ushort*)w;  w += (size_t)T_ * 768 * 2;           // 22.1MB
  ushort* AOb   = (ushort*)w;  w += (size_t)T_ * 256 * 2;           // 7.37MB (also SMPb)
  float*  CT    = (float*)w;   w += (size_t)T_ * 256 * 4;           // 14.7MB
  ushort* CTb   = (ushort*)w;  w += (size_t)T_ * 256 * 2;           // 7.37MB
  ushort* Vb    = (ushort*)w;  w += (size_t)(BS_ * LIN_) * 256 * 2; // 54.5MB (also Uff)
  float*  OFFAW = (float*)w;   w += (size_t)T_ * 384 * 4;           // 22.1MB
  float*  OAB   = (float*)w;   w += 384 * 4;                        // packed bias
  ushort* Uff   = Vb;
  ushort* SMPb  = AOb;
  float*  Bt    = (float*)d_out;

  ushort* W_across_in  = Wb + WOF0;
  ushort* W_within_in  = Wb + WOF1;
  ushort* W_across_out = Wb + WOF2;
  ushort* W_within_out = Wb + WOF3;
  ushort* W_offaw      = Wb + WOF4;   // off rows 0..255, aw rows 256..383
  ushort* W_val        = Wb + WOF6;
  ushort* W_msout      = Wb + WOF7;
  ushort* W_lin1       = Wb + WOF8;
  ushort* W_lin2       = Wb + WOF9;
  ushort* W_lin1p      = Wb + WOF10;
  ushort* W_lin2p      = Wb + WOF11;

  dim3 blk(256);
  const int MT = T_;                 // 14400
  const int MV = BS_ * LIN_;         // 106352
  const int MTt = (MT + 127) / 128;  // 113
  const int MVt = (MV + 127) / 128;  // 831
  dim3 gLN((MT + 3) / 4);

  // 0. weights -> bf16; pack off/aw bias
  conv_weights<<<dim3((WTOT / 8 + 255) / 256), blk, 0, stream>>>(
      across_in_w, within_in_w, across_out_w, within_out_w, off_w, aw_w,
      val_w, msout_w, lin1_w, lin2_w, lin1p_w, lin2p_w, Wb);
  pack_bias<<<dim3(1), dim3(384), 0, stream>>>(off_b, aw_b, OAB);
  // 1. across in-proj (f32 A) -> QKVb bf16
  gemm_mfma<0, true, 1><<<dim3(6, MTt), blk, 0, stream>>>(
      tgt, W_across_in, across_in_b, QKVb, MT, 768, 256);
  // 2. across attention (MFMA) -> AOb bf16
  attn_across_mfma<<<dim3(144 * 8), blk, 0, stream>>>(QKVb, AOb);
  // 3. across out-proj -> Bt f32
  gemm_mfma<0, false, 0><<<dim3(2, MTt), blk, 0, stream>>>(
      AOb, W_across_out, across_out_b, Bt, MT, 256, 256);
  // 4. CT = LN(tgt + Bt) + pos  (f32 + bf16)
  ln_res<<<gLN, blk, 0, stream>>>(tgt, Bt, across_norm_g, across_norm_b, pos, CT, CTb, MT);
  // 5. value projection -> Vb bf16
  gemm_mfma<1, true, 1><<<dim3(2, MVt), blk, 0, stream>>>(
      mem, W_val, val_b, Vb, MV, 256, 256);
  // 6. fused off+aw (AMODE2) -> OFFAW f32
  gemm_mfma<2, false, 0><<<dim3(3, MTt), blk, 0, stream>>>(
      CTb, W_offaw, OAB, OFFAW, MT, 384, 256);
  // 7. bilinear sampling -> SMPb bf16 (token order)
  deform_sample<<<dim3(T_ / 4), blk, 0, stream>>>(OFFAW, Vb, ref, SMPb);
  // 8. msout -> Bt
  gemm_mfma<0, false, 0><<<dim3(2, MTt), blk, 0, stream>>>(
      SMPb, W_msout, msout_b, Bt, MT, 256, 256);
  // 9. norm1
  ln_res<<<gLN, blk, 0, stream>>>(CT, Bt, norm1_g, norm1_b, nullptr, CT, CTb, MT);
  // 10. lin1 (+relu) -> Uff bf16
  gemm_mfma<0, false, 2><<<dim3(8, MTt), blk, 0, stream>>>(
      CTb, W_lin1, lin1_b, Uff, MT, 1024, 256);
  // 11. lin2 -> Bt
  gemm_mfma<0, false, 0><<<dim3(2, MTt), blk, 0, stream>>>(
      Uff, W_lin2, lin2_b, Bt, MT, 256, 1024);
  // 12. norm2 + pos
  ln_res<<<gLN, blk, 0, stream>>>(CT, Bt, norm2_g, norm2_b, pos, CT, CTb, MT);
  // 13. within in-proj -> QKVb bf16
  gemm_mfma<0, false, 1><<<dim3(6, MTt), blk, 0, stream>>>(
      CTb, W_within_in, within_in_b, QKVb, MT, 768, 256);
  // 14. within attention -> AOb bf16
  attn_within<<<dim3(NQ_ * BS_), blk, 0, stream>>>(QKVb, AOb);
  // 15. within out-proj -> Bt
  gemm_mfma<0, false, 0><<<dim3(2, MTt), blk, 0, stream>>>(
      AOb, W_within_out, within_out_b, Bt, MT, 256, 256);
  // 16. within_norm
  ln_res<<<gLN, blk, 0, stream>>>(CT, Bt, within_norm_g, within_norm_b, nullptr, CT, CTb, MT);
  // 17. lin1p (+relu) -> Uff
  gemm_mfma<0, false, 2><<<dim3(8, MTt), blk, 0, stream>>>(
      CTb, W_lin1p, lin1p_b, Uff, MT, 1024, 256);
  // 18. lin2p -> Bt
  gemm_mfma<0, false, 0><<<dim3(2, MTt), blk, 0, stream>>>(
      Uff, W_lin2p, lin2p_b, Bt, MT, 256, 1024);
  // 19. final norm2p -> d_out (f32 only)
  ln_res<<<gLN, blk, 0, stream>>>(CT, Bt, norm2p_g, norm2p_b, nullptr, (float*)d_out, nullptr, MT);
}